// Round 3
// baseline (1209.214 us; speedup 1.0000x reference)
//
#include <hip/hip_runtime.h>

// ContextualSimilarity, N=8192 D=512 K=5, MI355X gfx950.  v3 == v2 (re-audited;
// v2 never ran: GPU at capacity).  Sparse rewrite, ws ~= 144.7 MiB.
//
// Column j of mask has exactly 5 ones (+ties): kth[j] = 5th smallest of row j
// and dist is symmetric. So:
//   colIdx[j][0..cnt_j) = { i : dist(j,i) <= kth[j] }   (cnt_j ~ 5, cap 16)
//   rs[i]   = #appearances of i across all col lists (row sums of mask)
//   ridx[j] = { k in colIdx[j] : j in colIdx[k] }  (R row lists, <= cnt_j)
//   C[a][b] = sum_j [a,b in colIdx[j]]  -> ~205K scatter-adds into dense u16
//   X[i][j] = (sum_{k in ridx[j]} C[i][k]) / (rs_i * rR_i)
//   out     = 0.5*(X + X^T)
//
// dist lives in d_out (dead before X written).

#define N 8192
#define DIM 512
#define KNN 5

typedef _Float16 half_t;
typedef __attribute__((ext_vector_type(8))) _Float16 f16x8;
typedef __attribute__((ext_vector_type(4))) float f32x4;

#define GLOAD_LDS16(gp, lp) __builtin_amdgcn_global_load_lds( \
    (const __attribute__((address_space(1))) void*)(gp),      \
    (__attribute__((address_space(3))) void*)(lp), 16, 0, 0)

// ---------------------------------------------------------------- prep
__global__ __launch_bounds__(256) void prep_kernel(
    const float* __restrict__ z, half_t* __restrict__ zh,
    half_t* __restrict__ zl, float* __restrict__ sq) {
  const int row = blockIdx.x;
  const int t = threadIdx.x;
  float s = 0.f;
#pragma unroll
  for (int it = 0; it < DIM / 256; ++it) {
    const int c = t + it * 256;
    const float v = z[(size_t)row * DIM + c];
    s += v * v;
    const half_t h = (half_t)v;
    zh[(size_t)row * DIM + c] = h;
    zl[(size_t)row * DIM + c] = (half_t)(v - (float)h);
  }
  __shared__ float red[256];
  red[t] = s;
  __syncthreads();
  for (int st = 128; st > 0; st >>= 1) {
    if (t < st) red[t] += red[t + st];
    __syncthreads();
  }
  if (t == 0) sq[row] = red[0];
}

// ---------------------------------------------------------------- dist GEMM
// 128x128 tile, 4 waves (2x2), BK=32, fp16-split 3-MFMA accumulation.
__global__ __launch_bounds__(256) void gemm_dist(
    const half_t* __restrict__ zh, const half_t* __restrict__ zl,
    const float* __restrict__ sq, float* __restrict__ dist) {
  __shared__ __align__(16) half_t sAh[128 * 32], sAl[128 * 32];
  __shared__ __align__(16) half_t sBh[128 * 32], sBl[128 * 32];
  const int id = blockIdx.y * gridDim.x + blockIdx.x;      // XCD swizzle (T1)
  const int swz = (id & 7) * ((64 * 64) >> 3) + (id >> 3); // 4096 % 8 == 0
  const int bi = swz & 63, bj = swz >> 6;
  const int tid = threadIdx.x;
  const int lane = tid & 63, wave = tid >> 6;
  const int wr = wave >> 1, wc = wave & 1;
  const int r0 = tid >> 2, c0 = (tid & 3) * 8;

  f32x4 acc[4][4] = {};

  const size_t a0 = (size_t)(bi * 128 + r0) * DIM + c0;
  const size_t a1 = a0 + (size_t)64 * DIM;
  const size_t b0 = (size_t)(bj * 128 + r0) * DIM + c0;
  const size_t b1 = b0 + (size_t)64 * DIM;
  const int l0 = r0 * 32 + c0, l1 = l0 + 64 * 32;

  for (int k0 = 0; k0 < DIM; k0 += 32) {
    GLOAD_LDS16(zh + a0 + k0, &sAh[l0]);
    GLOAD_LDS16(zh + a1 + k0, &sAh[l1]);
    GLOAD_LDS16(zl + a0 + k0, &sAl[l0]);
    GLOAD_LDS16(zl + a1 + k0, &sAl[l1]);
    GLOAD_LDS16(zh + b0 + k0, &sBh[l0]);
    GLOAD_LDS16(zh + b1 + k0, &sBh[l1]);
    GLOAD_LDS16(zl + b0 + k0, &sBl[l0]);
    GLOAD_LDS16(zl + b1 + k0, &sBl[l1]);
    __syncthreads();
    const int lr = lane & 15, lk = (lane >> 4) * 8;
    f16x8 ah[4], al[4], bh[4], bl[4];
#pragma unroll
    for (int m = 0; m < 4; ++m) {
      const int off = (wr * 64 + m * 16 + lr) * 32 + lk;
      ah[m] = *(const f16x8*)&sAh[off];
      al[m] = *(const f16x8*)&sAl[off];
    }
#pragma unroll
    for (int n = 0; n < 4; ++n) {
      const int off = (wc * 64 + n * 16 + lr) * 32 + lk;
      bh[n] = *(const f16x8*)&sBh[off];
      bl[n] = *(const f16x8*)&sBl[off];
    }
#pragma unroll
    for (int m = 0; m < 4; ++m)
#pragma unroll
      for (int n = 0; n < 4; ++n) {
        acc[m][n] = __builtin_amdgcn_mfma_f32_16x16x32_f16(ah[m], bh[n], acc[m][n], 0, 0, 0);
        acc[m][n] = __builtin_amdgcn_mfma_f32_16x16x32_f16(ah[m], bl[n], acc[m][n], 0, 0, 0);
        acc[m][n] = __builtin_amdgcn_mfma_f32_16x16x32_f16(al[m], bh[n], acc[m][n], 0, 0, 0);
      }
    __syncthreads();
  }

  // C/D layout: col = lane&15, row = (lane>>4)*4 + reg  [measured m89/m91]
  const int lcol = lane & 15, lr4 = (lane >> 4) * 4;
#pragma unroll
  for (int m = 0; m < 4; ++m)
#pragma unroll
    for (int rr = 0; rr < 4; ++rr) {
      const int grow = bi * 128 + wr * 64 + m * 16 + lr4 + rr;
      const float sqi = sq[grow];
#pragma unroll
      for (int n = 0; n < 4; ++n) {
        const int gcol = bj * 128 + wc * 64 + n * 16 + lcol;
        const float d2 = sqi + sq[gcol] - 2.0f * acc[m][n][rr];
        dist[(size_t)grow * N + gcol] = sqrtf(fmaxf(d2, 0.f));
      }
    }
}

// --------------------------------------------------- top-5 + column collect
__global__ __launch_bounds__(256) void topk_collect(
    const float* __restrict__ dist, unsigned short* __restrict__ colIdx,
    int* __restrict__ colCnt, float* __restrict__ rs) {
  const int row = blockIdx.x;
  const int tid = threadIdx.x;
  const float* dr = dist + (size_t)row * N;
  float t[KNN] = {1e30f, 1e30f, 1e30f, 1e30f, 1e30f};
#define INS(val)                                                  \
  {                                                               \
    float v_ = (val);                                             \
    if (v_ < t[4]) {                                              \
      t[4] = v_;                                                  \
      if (t[4] < t[3]) { float x = t[3]; t[3] = t[4]; t[4] = x; } \
      if (t[3] < t[2]) { float x = t[2]; t[2] = t[3]; t[3] = x; } \
      if (t[2] < t[1]) { float x = t[1]; t[1] = t[2]; t[2] = x; } \
      if (t[1] < t[0]) { float x = t[0]; t[0] = t[1]; t[1] = x; } \
    }                                                             \
  }
  for (int c = tid * 4; c < N; c += 1024) {
    float4 v = *(const float4*)&dr[c];
    INS(v.x); INS(v.y); INS(v.z); INS(v.w);
  }
#undef INS
  __shared__ float cand[256 * KNN];
#pragma unroll
  for (int i = 0; i < KNN; ++i) cand[tid + 256 * i] = t[i];
  __syncthreads();
  __shared__ float rv[256];
  __shared__ int ri[256];
  float kv = 0.f;
  for (int round = 0; round < KNN; ++round) {
    float best = 1e30f;
    int bidx = 0;
#pragma unroll
    for (int i = 0; i < KNN; ++i) {
      float v = cand[tid + 256 * i];
      if (v < best) { best = v; bidx = tid + 256 * i; }
    }
    rv[tid] = best;
    ri[tid] = bidx;
    __syncthreads();
    for (int st = 128; st > 0; st >>= 1) {
      if (tid < st && rv[tid + st] < rv[tid]) {
        rv[tid] = rv[tid + st];
        ri[tid] = ri[tid + st];
      }
      __syncthreads();
    }
    kv = rv[0];
    if (tid == 0) cand[ri[0]] = 1e30f;
    __syncthreads();
  }
  // pass 2: collect ALL i with dist(row,i) <= kv (handles ties), cap 16.
  // Row is L1/L2-hot from pass 1.
  __shared__ int scnt;
  if (tid == 0) scnt = 0;
  __syncthreads();
  for (int c = tid * 4; c < N; c += 1024) {
    float4 v = *(const float4*)&dr[c];
#pragma unroll
    for (int u = 0; u < 4; ++u) {
      const float d = (u == 0) ? v.x : (u == 1) ? v.y : (u == 2) ? v.z : v.w;
      if (d <= kv) {
        const int p = atomicAdd(&scnt, 1);
        if (p < 16) {
          colIdx[row * 16 + p] = (unsigned short)(c + u);
          atomicAdd(&rs[c + u], 1.0f);  // rs[i] = row-sum of mask
        }
      }
    }
  }
  __syncthreads();
  if (tid == 0) colCnt[row] = (scnt < 16) ? scnt : 16;
}

// ---------------------------------------------------------------- R lists
__global__ __launch_bounds__(256) void rlist_kernel(
    const unsigned short* __restrict__ colIdx, const int* __restrict__ colCnt,
    unsigned short* __restrict__ ridx, int* __restrict__ rcnt,
    float* __restrict__ rRf) {
  const int j = blockIdx.x * 256 + threadIdx.x;
  if (j >= N) return;
  const int cj = colCnt[j];
  int rc = 0;
  for (int t = 0; t < cj; ++t) {
    const int k = colIdx[j * 16 + t];
    const int ck = colCnt[k];
    bool found = false;
    for (int u = 0; u < ck; ++u) found |= (colIdx[k * 16 + u] == (unsigned short)j);
    if (found) { ridx[j * 16 + rc] = (unsigned short)k; ++rc; }
  }
  rcnt[j] = rc;
  rRf[j] = (float)rc;  // >= 1 always (diag of R)
}

// ------------------------------------------------------------- C scatter
// C[a][b] += 1 for all (a,b) in colIdx[j]^2; C is dense uint16 (row-major),
// updated via uint32-word integer atomics (exact; counts << 65536 so no
// cross-halfword carry).
__global__ __launch_bounds__(256) void cscatter_kernel(
    const unsigned short* __restrict__ colIdx, const int* __restrict__ colCnt,
    unsigned int* __restrict__ Cw) {
  const int j = blockIdx.x * 256 + threadIdx.x;
  if (j >= N) return;
  const int cj = colCnt[j];
  for (int a = 0; a < cj; ++a) {
    const size_t rowoff = (size_t)colIdx[j * 16 + a] * N;
    for (int b = 0; b < cj; ++b) {
      const size_t e = rowoff + colIdx[j * 16 + b];
      atomicAdd(&Cw[e >> 1], 1u << ((e & 1) * 16));
    }
  }
}

// ---------------------------------------------------------------- X gather
// Block stages 4 rows of C in LDS; X[i][j] = sum_{k in ridx[j]} C[i][k] * s_i.
__global__ __launch_bounds__(256) void xgather_kernel(
    const unsigned short* __restrict__ Cm, const unsigned short* __restrict__ ridx,
    const int* __restrict__ rcnt, const float* __restrict__ rs,
    const float* __restrict__ rRf, float* __restrict__ X) {
  __shared__ unsigned short cs[4 * N];  // 64 KiB
  __shared__ float ssc[4];
  const int i0 = blockIdx.x * 4;
  const int tid = threadIdx.x;
  const uint4* src = (const uint4*)(Cm + (size_t)i0 * N);
  uint4* dst = (uint4*)cs;
#pragma unroll
  for (int t = 0; t < 16; ++t) dst[tid + t * 256] = src[tid + t * 256];
  if (tid < 4) ssc[tid] = 1.0f / (rs[i0 + tid] * rRf[i0 + tid]);
  __syncthreads();
#pragma unroll 1
  for (int jt = 0; jt < N / 256; ++jt) {
    const int j = jt * 256 + tid;
    const int rc = rcnt[j];
    float acc0 = 0.f, acc1 = 0.f, acc2 = 0.f, acc3 = 0.f;
    for (int t = 0; t < rc; ++t) {
      const int k = ridx[j * 16 + t];
      acc0 += (float)cs[k];
      acc1 += (float)cs[N + k];
      acc2 += (float)cs[2 * N + k];
      acc3 += (float)cs[3 * N + k];
    }
    X[(size_t)(i0 + 0) * N + j] = acc0 * ssc[0];
    X[(size_t)(i0 + 1) * N + j] = acc1 * ssc[1];
    X[(size_t)(i0 + 2) * N + j] = acc2 * ssc[2];
    X[(size_t)(i0 + 3) * N + j] = acc3 * ssc[3];
  }
}

// ---------------------------------------------------------------- symmetrize
__global__ __launch_bounds__(256) void sym_kernel(float* __restrict__ out) {
  const int bi = blockIdx.x, bj = blockIdx.y;
  if (bj < bi) return;
  __shared__ __align__(16) float t1[64][68], t2[64][68];
  const int r = threadIdx.x >> 2, q = threadIdx.x & 3;
  const size_t row1 = (size_t)(bi * 64 + r) * N + bj * 64;
  const size_t row2 = (size_t)(bj * 64 + r) * N + bi * 64;
#pragma unroll
  for (int s = 0; s < 16; s += 4)
    *(float4*)&t1[r][q * 16 + s] = *(const float4*)&out[row1 + q * 16 + s];
  if (bi != bj) {
#pragma unroll
    for (int s = 0; s < 16; s += 4)
      *(float4*)&t2[r][q * 16 + s] = *(const float4*)&out[row2 + q * 16 + s];
  }
  __syncthreads();
  if (bi == bj) {
#pragma unroll
    for (int s = 0; s < 16; ++s) {
      const int c = q * 16 + s;
      out[row1 + c] = 0.5f * (t1[r][c] + t1[c][r]);
    }
  } else {
#pragma unroll
    for (int s = 0; s < 16; ++s) {
      const int c = q * 16 + s;
      out[row1 + c] = 0.5f * (t1[r][c] + t2[c][r]);
      out[row2 + c] = 0.5f * (t2[r][c] + t1[c][r]);
    }
  }
}

// ---------------------------------------------------------------- launch
extern "C" void kernel_launch(void* const* d_in, const int* in_sizes, int n_in,
                              void* d_out, int out_size, void* d_ws,
                              size_t ws_size, hipStream_t stream) {
  const float* z = (const float*)d_in[0];
  float* out = (float*)d_out;
  char* ws = (char*)d_ws;

  // ws layout
  unsigned short* Cm = (unsigned short*)ws;                 // 128 MiB dense C
  half_t* zh = (half_t*)(ws + 134217728ull);                // 8 MiB
  half_t* zl = (half_t*)(ws + 142606336ull);                // 8 MiB
  unsigned short* colIdx = (unsigned short*)(ws + 150994944ull);  // 256 KiB
  unsigned short* ridx = (unsigned short*)(ws + 151257088ull);    // 256 KiB
  int* colCnt = (int*)(ws + 151519232ull);                  // 32 KiB
  int* rcnt = (int*)(ws + 151552000ull);                    // 32 KiB
  float* rs = (float*)(ws + 151584768ull);                  // 32 KiB
  float* rRf = (float*)(ws + 151617536ull);                 // 32 KiB
  float* sq = (float*)(ws + 151650304ull);                  // 32 KiB
  const size_t WS_NEEDED = 151683072ull;                    // ~144.7 MiB
  if (ws_size < WS_NEEDED) return;

  float* dist = out;  // d_out hosts dist until xgather overwrites it

  hipMemsetAsync(rs, 0, N * sizeof(float), stream);
  hipMemsetAsync(Cm, 0, (size_t)N * N * sizeof(unsigned short), stream);
  prep_kernel<<<N, 256, 0, stream>>>(z, zh, zl, sq);
  gemm_dist<<<dim3(64, 64), 256, 0, stream>>>(zh, zl, sq, dist);
  topk_collect<<<N, 256, 0, stream>>>(dist, colIdx, colCnt, rs);
  rlist_kernel<<<N / 256, 256, 0, stream>>>(colIdx, colCnt, ridx, rcnt, rRf);
  cscatter_kernel<<<N / 256, 256, 0, stream>>>(colIdx, colCnt, (unsigned int*)Cm);
  xgather_kernel<<<N / 4, 256, 0, stream>>>(Cm, ridx, rcnt, rs, rRf, out);
  sym_kernel<<<dim3(128, 128), 256, 0, stream>>>(out);
}

// Round 4
// 876.937 us; speedup vs baseline: 1.3789x; 1.3789x over previous
//
#include <hip/hip_runtime.h>

// ContextualSimilarity, N=8192 D=512 K=5, MI355X gfx950.  v4.
//
// v3 passed at 1209us; sym_kernel was top dispatch (393us, 8.4M LDS bank
// conflicts from even-stride padding, 24% occupancy). v4:
//  - symgather: fused xgather+sym via C symmetry:
//      out[i][j] = 0.5*s_i*sum_{k in ridx[j]} C[i][k]
//                + 0.5*s_j*sum_{k in ridx[i]} C[k][j]
//    (second term = coalesced streams of <=20 C rows per block, L3-hot).
//    Deletes X write/read and sym entirely.
//  - topk_collect: single-pass (index-tracked register candidates), no
//    global re-read for the collect phase.
//
// Pipeline: prep -> gemm_dist(d_out as dist) -> topk_collect -> rlist ->
//           cscatter -> symgather(-> d_out).   ws ~= 144.7 MiB.

#define N 8192
#define DIM 512
#define KNN 5

typedef _Float16 half_t;
typedef __attribute__((ext_vector_type(8))) _Float16 f16x8;
typedef __attribute__((ext_vector_type(4))) float f32x4;
typedef __attribute__((ext_vector_type(8))) unsigned short ushort8;

#define GLOAD_LDS16(gp, lp) __builtin_amdgcn_global_load_lds( \
    (const __attribute__((address_space(1))) void*)(gp),      \
    (__attribute__((address_space(3))) void*)(lp), 16, 0, 0)

// ---------------------------------------------------------------- prep
__global__ __launch_bounds__(256) void prep_kernel(
    const float* __restrict__ z, half_t* __restrict__ zh,
    half_t* __restrict__ zl, float* __restrict__ sq) {
  const int row = blockIdx.x;
  const int t = threadIdx.x;
  float s = 0.f;
#pragma unroll
  for (int it = 0; it < DIM / 256; ++it) {
    const int c = t + it * 256;
    const float v = z[(size_t)row * DIM + c];
    s += v * v;
    const half_t h = (half_t)v;
    zh[(size_t)row * DIM + c] = h;
    zl[(size_t)row * DIM + c] = (half_t)(v - (float)h);
  }
  __shared__ float red[256];
  red[t] = s;
  __syncthreads();
  for (int st = 128; st > 0; st >>= 1) {
    if (t < st) red[t] += red[t + st];
    __syncthreads();
  }
  if (t == 0) sq[row] = red[0];
}

// ---------------------------------------------------------------- dist GEMM
// 128x128 tile, 4 waves (2x2), BK=32, fp16-split 3-MFMA accumulation.
__global__ __launch_bounds__(256) void gemm_dist(
    const half_t* __restrict__ zh, const half_t* __restrict__ zl,
    const float* __restrict__ sq, float* __restrict__ dist) {
  __shared__ __align__(16) half_t sAh[128 * 32], sAl[128 * 32];
  __shared__ __align__(16) half_t sBh[128 * 32], sBl[128 * 32];
  const int id = blockIdx.y * gridDim.x + blockIdx.x;      // XCD swizzle (T1)
  const int swz = (id & 7) * ((64 * 64) >> 3) + (id >> 3); // 4096 % 8 == 0
  const int bi = swz & 63, bj = swz >> 6;
  const int tid = threadIdx.x;
  const int lane = tid & 63, wave = tid >> 6;
  const int wr = wave >> 1, wc = wave & 1;
  const int r0 = tid >> 2, c0 = (tid & 3) * 8;

  f32x4 acc[4][4] = {};

  const size_t a0 = (size_t)(bi * 128 + r0) * DIM + c0;
  const size_t a1 = a0 + (size_t)64 * DIM;
  const size_t b0 = (size_t)(bj * 128 + r0) * DIM + c0;
  const size_t b1 = b0 + (size_t)64 * DIM;
  const int l0 = r0 * 32 + c0, l1 = l0 + 64 * 32;

  for (int k0 = 0; k0 < DIM; k0 += 32) {
    GLOAD_LDS16(zh + a0 + k0, &sAh[l0]);
    GLOAD_LDS16(zh + a1 + k0, &sAh[l1]);
    GLOAD_LDS16(zl + a0 + k0, &sAl[l0]);
    GLOAD_LDS16(zl + a1 + k0, &sAl[l1]);
    GLOAD_LDS16(zh + b0 + k0, &sBh[l0]);
    GLOAD_LDS16(zh + b1 + k0, &sBh[l1]);
    GLOAD_LDS16(zl + b0 + k0, &sBl[l0]);
    GLOAD_LDS16(zl + b1 + k0, &sBl[l1]);
    __syncthreads();
    const int lr = lane & 15, lk = (lane >> 4) * 8;
    f16x8 ah[4], al[4], bh[4], bl[4];
#pragma unroll
    for (int m = 0; m < 4; ++m) {
      const int off = (wr * 64 + m * 16 + lr) * 32 + lk;
      ah[m] = *(const f16x8*)&sAh[off];
      al[m] = *(const f16x8*)&sAl[off];
    }
#pragma unroll
    for (int n = 0; n < 4; ++n) {
      const int off = (wc * 64 + n * 16 + lr) * 32 + lk;
      bh[n] = *(const f16x8*)&sBh[off];
      bl[n] = *(const f16x8*)&sBl[off];
    }
#pragma unroll
    for (int m = 0; m < 4; ++m)
#pragma unroll
      for (int n = 0; n < 4; ++n) {
        acc[m][n] = __builtin_amdgcn_mfma_f32_16x16x32_f16(ah[m], bh[n], acc[m][n], 0, 0, 0);
        acc[m][n] = __builtin_amdgcn_mfma_f32_16x16x32_f16(ah[m], bl[n], acc[m][n], 0, 0, 0);
        acc[m][n] = __builtin_amdgcn_mfma_f32_16x16x32_f16(al[m], bh[n], acc[m][n], 0, 0, 0);
      }
    __syncthreads();
  }

  // C/D layout: col = lane&15, row = (lane>>4)*4 + reg  [measured m89/m91]
  const int lcol = lane & 15, lr4 = (lane >> 4) * 4;
#pragma unroll
  for (int m = 0; m < 4; ++m)
#pragma unroll
    for (int rr = 0; rr < 4; ++rr) {
      const int grow = bi * 128 + wr * 64 + m * 16 + lr4 + rr;
      const float sqi = sq[grow];
#pragma unroll
      for (int n = 0; n < 4; ++n) {
        const int gcol = bj * 128 + wc * 64 + n * 16 + lcol;
        const float d2 = sqi + sq[gcol] - 2.0f * acc[m][n][rr];
        dist[(size_t)grow * N + gcol] = sqrtf(fmaxf(d2, 0.f));
      }
    }
}

// --------------------------------- top-5 + collect (single pass over dist)
__global__ __launch_bounds__(256) void topk_collect(
    const float* __restrict__ dist, unsigned short* __restrict__ colIdx,
    int* __restrict__ colCnt, float* __restrict__ rs) {
  const int row = blockIdx.x;
  const int tid = threadIdx.x;
  const float* dr = dist + (size_t)row * N;
  float tv[KNN] = {1e30f, 1e30f, 1e30f, 1e30f, 1e30f};
  int tix[KNN] = {0, 0, 0, 0, 0};
#define INS(val, idx)                                             \
  {                                                               \
    const float v_ = (val);                                       \
    if (v_ < tv[4]) {                                             \
      tv[4] = v_; tix[4] = (idx);                                 \
      if (tv[4] < tv[3]) { float x = tv[3]; tv[3] = tv[4]; tv[4] = x; \
                           int y = tix[3]; tix[3] = tix[4]; tix[4] = y; } \
      if (tv[3] < tv[2]) { float x = tv[2]; tv[2] = tv[3]; tv[3] = x; \
                           int y = tix[2]; tix[2] = tix[3]; tix[3] = y; } \
      if (tv[2] < tv[1]) { float x = tv[1]; tv[1] = tv[2]; tv[2] = x; \
                           int y = tix[1]; tix[1] = tix[2]; tix[2] = y; } \
      if (tv[1] < tv[0]) { float x = tv[0]; tv[0] = tv[1]; tv[1] = x; \
                           int y = tix[0]; tix[0] = tix[1]; tix[1] = y; } \
    }                                                             \
  }
  for (int c = tid * 4; c < N; c += 1024) {
    float4 v = *(const float4*)&dr[c];
    INS(v.x, c); INS(v.y, c + 1); INS(v.z, c + 2); INS(v.w, c + 3);
  }
#undef INS
  __shared__ float cand[256 * KNN];
#pragma unroll
  for (int i = 0; i < KNN; ++i) cand[tid + 256 * i] = tv[i];
  __syncthreads();
  __shared__ float rv[256];
  __shared__ int ri[256];
  float kv = 0.f;
  for (int round = 0; round < KNN; ++round) {
    float best = 1e30f;
    int bidx = 0;
#pragma unroll
    for (int i = 0; i < KNN; ++i) {
      float v = cand[tid + 256 * i];
      if (v < best) { best = v; bidx = tid + 256 * i; }
    }
    rv[tid] = best;
    ri[tid] = bidx;
    __syncthreads();
    for (int st = 128; st > 0; st >>= 1) {
      if (tid < st && rv[tid + st] < rv[tid]) {
        rv[tid] = rv[tid + st];
        ri[tid] = ri[tid + st];
      }
      __syncthreads();
    }
    kv = rv[0];
    if (tid == 0) cand[ri[0]] = 1e30f;
    __syncthreads();
  }
  // Emit register candidates <= kv (kv = 5th smallest; ties beyond a
  // thread's top-5 are measure-zero for continuous data). Cap 16.
  __shared__ int scnt;
  if (tid == 0) scnt = 0;
  __syncthreads();
#pragma unroll
  for (int t = 0; t < KNN; ++t) {
    if (tv[t] <= kv) {
      const int p = atomicAdd(&scnt, 1);
      if (p < 16) {
        colIdx[row * 16 + p] = (unsigned short)tix[t];
        atomicAdd(&rs[tix[t]], 1.0f);  // rs[i] = row-sum of mask
      }
    }
  }
  __syncthreads();
  if (tid == 0) colCnt[row] = (scnt < 16) ? scnt : 16;
}

// ---------------------------------------------------------------- R lists
__global__ __launch_bounds__(256) void rlist_kernel(
    const unsigned short* __restrict__ colIdx, const int* __restrict__ colCnt,
    unsigned short* __restrict__ ridx, int* __restrict__ rcnt,
    float* __restrict__ rRf) {
  const int j = blockIdx.x * 256 + threadIdx.x;
  if (j >= N) return;
  const int cj = colCnt[j];
  int rc = 0;
  for (int t = 0; t < cj; ++t) {
    const int k = colIdx[j * 16 + t];
    const int ck = colCnt[k];
    bool found = false;
    for (int u = 0; u < ck; ++u) found |= (colIdx[k * 16 + u] == (unsigned short)j);
    if (found) { ridx[j * 16 + rc] = (unsigned short)k; ++rc; }
  }
  rcnt[j] = rc;
  rRf[j] = (float)rc;  // >= 1 always (diag of R)
}

// ------------------------------------------------------------- C scatter
// C[a][b] += 1 for all (a,b) in colIdx[j]^2; dense u16, u32-word atomics.
__global__ __launch_bounds__(256) void cscatter_kernel(
    const unsigned short* __restrict__ colIdx, const int* __restrict__ colCnt,
    unsigned int* __restrict__ Cw) {
  const int j = blockIdx.x * 256 + threadIdx.x;
  if (j >= N) return;
  const int cj = colCnt[j];
  for (int a = 0; a < cj; ++a) {
    const size_t rowoff = (size_t)colIdx[j * 16 + a] * N;
    for (int b = 0; b < cj; ++b) {
      const size_t e = rowoff + colIdx[j * 16 + b];
      atomicAdd(&Cw[e >> 1], 1u << ((e & 1) * 16));
    }
  }
}

// ------------------------------------------------- fused gather + symmetrize
// Block owns 4 output rows. out[i][j] = g_ij*s_i*0.5 + h_ij*s_j*0.5 where
//   g_ij = sum_{k in ridx[j]} cs[i][k]        (LDS gather, staged C rows)
//   h_ij = sum_{k in ridx[i]} C[k][j]         (coalesced C-row streams, C=C^T)
__global__ __launch_bounds__(256) void symgather_kernel(
    const unsigned short* __restrict__ Cm, const unsigned short* __restrict__ ridx,
    const int* __restrict__ rcnt, const float* __restrict__ rs,
    const float* __restrict__ rRf, float* __restrict__ out) {
  __shared__ unsigned short cs[4 * N];  // 64 KiB
  __shared__ float shalf[4];
  __shared__ unsigned short kl[4][16];
  __shared__ int kc[4];
  const int i0 = blockIdx.x * 4;
  const int tid = threadIdx.x;
  const uint4* src = (const uint4*)(Cm + (size_t)i0 * N);
  uint4* dst = (uint4*)cs;
#pragma unroll
  for (int t = 0; t < 16; ++t) dst[tid + t * 256] = src[tid + t * 256];
  if (tid < 4) {
    shalf[tid] = 0.5f / (rs[i0 + tid] * rRf[i0 + tid]);
    kc[tid] = rcnt[i0 + tid];
  }
  if (tid < 64) kl[tid >> 4][tid & 15] = ridx[(i0 + (tid >> 4)) * 16 + (tid & 15)];
  __syncthreads();
  const float s0 = shalf[0], s1 = shalf[1], s2 = shalf[2], s3 = shalf[3];
#pragma unroll 1
  for (int jt = 0; jt < N / 2048; ++jt) {
    const int j0 = jt * 2048 + tid * 8;
    float h0[8] = {}, h1[8] = {}, h2[8] = {}, h3[8] = {};
    // H: stream ridx[i] rows of C (block-uniform loop counts -> no divergence)
    {
      const int c = kc[0];
      for (int t = 0; t < c; ++t) {
        const ushort8 v = *(const ushort8*)(Cm + (size_t)kl[0][t] * N + j0);
#pragma unroll
        for (int u = 0; u < 8; ++u) h0[u] += (float)v[u];
      }
    }
    {
      const int c = kc[1];
      for (int t = 0; t < c; ++t) {
        const ushort8 v = *(const ushort8*)(Cm + (size_t)kl[1][t] * N + j0);
#pragma unroll
        for (int u = 0; u < 8; ++u) h1[u] += (float)v[u];
      }
    }
    {
      const int c = kc[2];
      for (int t = 0; t < c; ++t) {
        const ushort8 v = *(const ushort8*)(Cm + (size_t)kl[2][t] * N + j0);
#pragma unroll
        for (int u = 0; u < 8; ++u) h2[u] += (float)v[u];
      }
    }
    {
      const int c = kc[3];
      for (int t = 0; t < c; ++t) {
        const ushort8 v = *(const ushort8*)(Cm + (size_t)kl[3][t] * N + j0);
#pragma unroll
        for (int u = 0; u < 8; ++u) h3[u] += (float)v[u];
      }
    }
    // G: LDS gather per j + combine + write
    float o0[8], o1[8], o2[8], o3[8];
#pragma unroll
    for (int ji = 0; ji < 8; ++ji) {
      const int j = j0 + ji;
      const int rc = rcnt[j];
      float g0 = 0.f, g1 = 0.f, g2 = 0.f, g3 = 0.f;
      for (int t = 0; t < rc; ++t) {
        const int k = ridx[j * 16 + t];
        g0 += (float)cs[k];
        g1 += (float)cs[N + k];
        g2 += (float)cs[2 * N + k];
        g3 += (float)cs[3 * N + k];
      }
      const float sj = 0.5f / (rs[j] * rRf[j]);
      o0[ji] = g0 * s0 + h0[ji] * sj;
      o1[ji] = g1 * s1 + h1[ji] * sj;
      o2[ji] = g2 * s2 + h2[ji] * sj;
      o3[ji] = g3 * s3 + h3[ji] * sj;
    }
    float* p0 = out + (size_t)(i0 + 0) * N + j0;
    float* p1 = out + (size_t)(i0 + 1) * N + j0;
    float* p2 = out + (size_t)(i0 + 2) * N + j0;
    float* p3 = out + (size_t)(i0 + 3) * N + j0;
    *(float4*)p0 = make_float4(o0[0], o0[1], o0[2], o0[3]);
    *(float4*)(p0 + 4) = make_float4(o0[4], o0[5], o0[6], o0[7]);
    *(float4*)p1 = make_float4(o1[0], o1[1], o1[2], o1[3]);
    *(float4*)(p1 + 4) = make_float4(o1[4], o1[5], o1[6], o1[7]);
    *(float4*)p2 = make_float4(o2[0], o2[1], o2[2], o2[3]);
    *(float4*)(p2 + 4) = make_float4(o2[4], o2[5], o2[6], o2[7]);
    *(float4*)p3 = make_float4(o3[0], o3[1], o3[2], o3[3]);
    *(float4*)(p3 + 4) = make_float4(o3[4], o3[5], o3[6], o3[7]);
  }
}

// ---------------------------------------------------------------- launch
extern "C" void kernel_launch(void* const* d_in, const int* in_sizes, int n_in,
                              void* d_out, int out_size, void* d_ws,
                              size_t ws_size, hipStream_t stream) {
  const float* z = (const float*)d_in[0];
  float* out = (float*)d_out;
  char* ws = (char*)d_ws;

  // ws layout
  unsigned short* Cm = (unsigned short*)ws;                 // 128 MiB dense C
  half_t* zh = (half_t*)(ws + 134217728ull);                // 8 MiB
  half_t* zl = (half_t*)(ws + 142606336ull);                // 8 MiB
  unsigned short* colIdx = (unsigned short*)(ws + 150994944ull);  // 256 KiB
  unsigned short* ridx = (unsigned short*)(ws + 151257088ull);    // 256 KiB
  int* colCnt = (int*)(ws + 151519232ull);                  // 32 KiB
  int* rcnt = (int*)(ws + 151552000ull);                    // 32 KiB
  float* rs = (float*)(ws + 151584768ull);                  // 32 KiB
  float* rRf = (float*)(ws + 151617536ull);                 // 32 KiB
  float* sq = (float*)(ws + 151650304ull);                  // 32 KiB
  const size_t WS_NEEDED = 151683072ull;                    // ~144.7 MiB
  if (ws_size < WS_NEEDED) return;

  float* dist = out;  // d_out hosts dist until symgather overwrites it

  hipMemsetAsync(rs, 0, N * sizeof(float), stream);
  hipMemsetAsync(Cm, 0, (size_t)N * N * sizeof(unsigned short), stream);
  prep_kernel<<<N, 256, 0, stream>>>(z, zh, zl, sq);
  gemm_dist<<<dim3(64, 64), 256, 0, stream>>>(zh, zl, sq, dist);
  topk_collect<<<N, 256, 0, stream>>>(dist, colIdx, colCnt, rs);
  rlist_kernel<<<N / 256, 256, 0, stream>>>(colIdx, colCnt, ridx, rcnt, rRf);
  cscatter_kernel<<<N / 256, 256, 0, stream>>>(colIdx, colCnt, (unsigned int*)Cm);
  symgather_kernel<<<N / 4, 256, 0, stream>>>(Cm, ridx, rcnt, rs, rRf, out);
}

// Round 6
// 699.961 us; speedup vs baseline: 1.7275x; 1.2528x over previous
//
#include <hip/hip_runtime.h>

// ContextualSimilarity, N=8192 D=512 K=5, MI355X gfx950.  v6 = v5 + CROW_CAP
// fix (512 -> 4096; hubness could overflow 512 and silently drop scatter
// contributions). v5 never ran (GPU at capacity).
//
// Sparse epilogue: C = M M^T has ~25 nnz/row, so
//   crow[k] = multiset {a : a,k in colIdx[j'] for some j'}  (mult = C[k][a])
//   for each j, k in ridx[j], a in crow[k]:
//       out[a][j] += 0.5*s_a ;  out[j][a] += 0.5*s_a      (s_a = 1/(rs_a*rR_a))
// after memset(out, 0). ~1.9M no-return float atomics replace v4's dense
// 420 MB gather/write kernel. dist (as d^2, sqrt dropped) lives in d_out
// until topk_collect finishes, then d_out is memset and scattered into.
//
// Pipeline: prep -> gemm_dist(d2 -> d_out) -> topk_collect -> rlist(+shalf) ->
//           crowbuild -> memset(d_out) -> scatter.   ws ~= 80.7 MiB.

#define N 8192
#define DIM 512
#define KNN 5
#define CROW_CAP 4096

typedef _Float16 half_t;
typedef __attribute__((ext_vector_type(8))) _Float16 f16x8;
typedef __attribute__((ext_vector_type(4))) float f32x4;

#define GLOAD_LDS16(gp, lp) __builtin_amdgcn_global_load_lds( \
    (const __attribute__((address_space(1))) void*)(gp),      \
    (__attribute__((address_space(3))) void*)(lp), 16, 0, 0)

// ---------------------------------------------------------------- prep
__global__ __launch_bounds__(256) void prep_kernel(
    const float* __restrict__ z, half_t* __restrict__ zh,
    half_t* __restrict__ zl, float* __restrict__ sq) {
  const int row = blockIdx.x;
  const int t = threadIdx.x;
  float s = 0.f;
#pragma unroll
  for (int it = 0; it < DIM / 256; ++it) {
    const int c = t + it * 256;
    const float v = z[(size_t)row * DIM + c];
    s += v * v;
    const half_t h = (half_t)v;
    zh[(size_t)row * DIM + c] = h;
    zl[(size_t)row * DIM + c] = (half_t)(v - (float)h);
  }
  __shared__ float red[256];
  red[t] = s;
  __syncthreads();
  for (int st = 128; st > 0; st >>= 1) {
    if (t < st) red[t] += red[t + st];
    __syncthreads();
  }
  if (t == 0) sq[row] = red[0];
}

// ---------------------------------------------------------------- dist GEMM
// 128x128 tile, 4 waves (2x2), BK=32, fp16-split 3-MFMA accumulation.
// Writes d^2 (no sqrt: top-k and thresholding are monotone-invariant).
__global__ __launch_bounds__(256) void gemm_dist(
    const half_t* __restrict__ zh, const half_t* __restrict__ zl,
    const float* __restrict__ sq, float* __restrict__ dist) {
  __shared__ __align__(16) half_t sAh[128 * 32], sAl[128 * 32];
  __shared__ __align__(16) half_t sBh[128 * 32], sBl[128 * 32];
  const int id = blockIdx.y * gridDim.x + blockIdx.x;      // XCD swizzle (T1)
  const int swz = (id & 7) * ((64 * 64) >> 3) + (id >> 3); // 4096 % 8 == 0
  const int bi = swz & 63, bj = swz >> 6;
  const int tid = threadIdx.x;
  const int lane = tid & 63, wave = tid >> 6;
  const int wr = wave >> 1, wc = wave & 1;
  const int r0 = tid >> 2, c0 = (tid & 3) * 8;

  f32x4 acc[4][4] = {};

  const size_t a0 = (size_t)(bi * 128 + r0) * DIM + c0;
  const size_t a1 = a0 + (size_t)64 * DIM;
  const size_t b0 = (size_t)(bj * 128 + r0) * DIM + c0;
  const size_t b1 = b0 + (size_t)64 * DIM;
  const int l0 = r0 * 32 + c0, l1 = l0 + 64 * 32;

  for (int k0 = 0; k0 < DIM; k0 += 32) {
    GLOAD_LDS16(zh + a0 + k0, &sAh[l0]);
    GLOAD_LDS16(zh + a1 + k0, &sAh[l1]);
    GLOAD_LDS16(zl + a0 + k0, &sAl[l0]);
    GLOAD_LDS16(zl + a1 + k0, &sAl[l1]);
    GLOAD_LDS16(zh + b0 + k0, &sBh[l0]);
    GLOAD_LDS16(zh + b1 + k0, &sBh[l1]);
    GLOAD_LDS16(zl + b0 + k0, &sBl[l0]);
    GLOAD_LDS16(zl + b1 + k0, &sBl[l1]);
    __syncthreads();
    const int lr = lane & 15, lk = (lane >> 4) * 8;
    f16x8 ah[4], al[4], bh[4], bl[4];
#pragma unroll
    for (int m = 0; m < 4; ++m) {
      const int off = (wr * 64 + m * 16 + lr) * 32 + lk;
      ah[m] = *(const f16x8*)&sAh[off];
      al[m] = *(const f16x8*)&sAl[off];
    }
#pragma unroll
    for (int n = 0; n < 4; ++n) {
      const int off = (wc * 64 + n * 16 + lr) * 32 + lk;
      bh[n] = *(const f16x8*)&sBh[off];
      bl[n] = *(const f16x8*)&sBl[off];
    }
#pragma unroll
    for (int m = 0; m < 4; ++m)
#pragma unroll
      for (int n = 0; n < 4; ++n) {
        acc[m][n] = __builtin_amdgcn_mfma_f32_16x16x32_f16(ah[m], bh[n], acc[m][n], 0, 0, 0);
        acc[m][n] = __builtin_amdgcn_mfma_f32_16x16x32_f16(ah[m], bl[n], acc[m][n], 0, 0, 0);
        acc[m][n] = __builtin_amdgcn_mfma_f32_16x16x32_f16(al[m], bh[n], acc[m][n], 0, 0, 0);
      }
    __syncthreads();
  }

  // C/D layout: col = lane&15, row = (lane>>4)*4 + reg  [measured m89/m91]
  const int lcol = lane & 15, lr4 = (lane >> 4) * 4;
#pragma unroll
  for (int m = 0; m < 4; ++m)
#pragma unroll
    for (int rr = 0; rr < 4; ++rr) {
      const int grow = bi * 128 + wr * 64 + m * 16 + lr4 + rr;
      const float sqi = sq[grow];
#pragma unroll
      for (int n = 0; n < 4; ++n) {
        const int gcol = bj * 128 + wc * 64 + n * 16 + lcol;
        const float d2 = sqi + sq[gcol] - 2.0f * acc[m][n][rr];
        dist[(size_t)grow * N + gcol] = fmaxf(d2, 0.f);
      }
    }
}

// --------------------------------- top-5 + collect (single pass over d2)
__global__ __launch_bounds__(256) void topk_collect(
    const float* __restrict__ dist, unsigned short* __restrict__ colIdx,
    int* __restrict__ colCnt, float* __restrict__ rs) {
  const int row = blockIdx.x;
  const int tid = threadIdx.x;
  const float* dr = dist + (size_t)row * N;
  float tv[KNN] = {1e30f, 1e30f, 1e30f, 1e30f, 1e30f};
  int tix[KNN] = {0, 0, 0, 0, 0};
#define INS(val, idx)                                             \
  {                                                               \
    const float v_ = (val);                                       \
    if (v_ < tv[4]) {                                             \
      tv[4] = v_; tix[4] = (idx);                                 \
      if (tv[4] < tv[3]) { float x = tv[3]; tv[3] = tv[4]; tv[4] = x; \
                           int y = tix[3]; tix[3] = tix[4]; tix[4] = y; } \
      if (tv[3] < tv[2]) { float x = tv[2]; tv[2] = tv[3]; tv[3] = x; \
                           int y = tix[2]; tix[2] = tix[3]; tix[3] = y; } \
      if (tv[2] < tv[1]) { float x = tv[1]; tv[1] = tv[2]; tv[2] = x; \
                           int y = tix[1]; tix[1] = tix[2]; tix[2] = y; } \
      if (tv[1] < tv[0]) { float x = tv[0]; tv[0] = tv[1]; tv[1] = x; \
                           int y = tix[0]; tix[0] = tix[1]; tix[1] = y; } \
    }                                                             \
  }
  for (int c = tid * 4; c < N; c += 1024) {
    float4 v = *(const float4*)&dr[c];
    INS(v.x, c); INS(v.y, c + 1); INS(v.z, c + 2); INS(v.w, c + 3);
  }
#undef INS
  __shared__ float cand[256 * KNN];
#pragma unroll
  for (int i = 0; i < KNN; ++i) cand[tid + 256 * i] = tv[i];
  __syncthreads();
  __shared__ float rv[256];
  __shared__ int ri[256];
  float kv = 0.f;
  for (int round = 0; round < KNN; ++round) {
    float best = 1e30f;
    int bidx = 0;
#pragma unroll
    for (int i = 0; i < KNN; ++i) {
      float v = cand[tid + 256 * i];
      if (v < best) { best = v; bidx = tid + 256 * i; }
    }
    rv[tid] = best;
    ri[tid] = bidx;
    __syncthreads();
    for (int st = 128; st > 0; st >>= 1) {
      if (tid < st && rv[tid + st] < rv[tid]) {
        rv[tid] = rv[tid + st];
        ri[tid] = ri[tid + st];
      }
      __syncthreads();
    }
    kv = rv[0];
    if (tid == 0) cand[ri[0]] = 1e30f;
    __syncthreads();
  }
  // Emit register candidates <= kv (kv = 5th smallest; ties beyond a
  // thread's top-5 are measure-zero for continuous data). Cap 16.
  __shared__ int scnt;
  if (tid == 0) scnt = 0;
  __syncthreads();
#pragma unroll
  for (int t = 0; t < KNN; ++t) {
    if (tv[t] <= kv) {
      const int p = atomicAdd(&scnt, 1);
      if (p < 16) {
        colIdx[row * 16 + p] = (unsigned short)tix[t];
        atomicAdd(&rs[tix[t]], 1.0f);  // rs[i] = row-sum of mask
      }
    }
  }
  __syncthreads();
  if (tid == 0) colCnt[row] = (scnt < 16) ? scnt : 16;
}

// ------------------------------------------------------- R lists + shalf
__global__ __launch_bounds__(256) void rlist_kernel(
    const unsigned short* __restrict__ colIdx, const int* __restrict__ colCnt,
    const float* __restrict__ rs, unsigned short* __restrict__ ridx,
    int* __restrict__ rcnt, float* __restrict__ shalf) {
  const int j = blockIdx.x * 256 + threadIdx.x;
  if (j >= N) return;
  const int cj = colCnt[j];
  int rc = 0;
  for (int t = 0; t < cj; ++t) {
    const int k = colIdx[j * 16 + t];
    const int ck = colCnt[k];
    bool found = false;
    for (int u = 0; u < ck; ++u) found |= (colIdx[k * 16 + u] == (unsigned short)j);
    if (found) { ridx[j * 16 + rc] = (unsigned short)k; ++rc; }
  }
  rcnt[j] = rc;                                  // rR_j >= 1 (diag of R)
  shalf[j] = 0.5f / (rs[j] * (float)rc);         // 0.5 * s_j
}

// ----------------------------------------------------- sparse C row build
// crow[k] = multiset of co-occurring indices (multiplicity = C[k][a]).
// crowCnt[k] ~= 5*rs[k]; CROW_CAP=4096 needs rs[k] > ~800 to overflow
// (impossible even with extreme hubness).
__global__ __launch_bounds__(256) void crowbuild_kernel(
    const unsigned short* __restrict__ colIdx, const int* __restrict__ colCnt,
    unsigned short* __restrict__ crow, int* __restrict__ crowCnt) {
  const int j = blockIdx.x * 256 + threadIdx.x;
  if (j >= N) return;
  const int cj = colCnt[j];
  unsigned short list[16];
  for (int t = 0; t < cj; ++t) list[t] = colIdx[j * 16 + t];
  for (int t = 0; t < cj; ++t) {
    const int k = list[t];
    const int base = atomicAdd(&crowCnt[k], cj);
    for (int u = 0; u < cj; ++u)
      if (base + u < CROW_CAP) crow[(size_t)k * CROW_CAP + base + u] = list[u];
  }
}

// ------------------------------------------------------------- scatter
// For each column j (wave per j): for k in ridx[j], a in crow[k]:
//   out[a][j] += 0.5*s_a ; out[j][a] += 0.5*s_a.  (no-return atomics)
__global__ __launch_bounds__(256) void scatter_kernel(
    const unsigned short* __restrict__ ridx, const int* __restrict__ rcnt,
    const unsigned short* __restrict__ crow, const int* __restrict__ crowCnt,
    const float* __restrict__ shalf, float* __restrict__ out) {
  const int tid = threadIdx.x;
  const int lane = tid & 63;
  const int j = blockIdx.x * 4 + (tid >> 6);
  const int rc = rcnt[j];
  for (int t = 0; t < rc; ++t) {
    const int k = ridx[j * 16 + t];
    int len = crowCnt[k];
    if (len > CROW_CAP) len = CROW_CAP;
    for (int e = lane; e < len; e += 64) {
      const int a = crow[(size_t)k * CROW_CAP + e];
      const float v = shalf[a];
      atomicAdd(&out[(size_t)a * N + j], v);
      atomicAdd(&out[(size_t)j * N + a], v);
    }
  }
}

// ---------------------------------------------------------------- launch
extern "C" void kernel_launch(void* const* d_in, const int* in_sizes, int n_in,
                              void* d_out, int out_size, void* d_ws,
                              size_t ws_size, hipStream_t stream) {
  const float* z = (const float*)d_in[0];
  float* out = (float*)d_out;
  char* ws = (char*)d_ws;

  // ws layout (~80.7 MiB)
  half_t* zh = (half_t*)ws;                                    // 8 MiB
  half_t* zl = (half_t*)(ws + 8388608ull);                     // 8 MiB
  unsigned short* crow = (unsigned short*)(ws + 16777216ull);  // 64 MiB
  unsigned short* colIdx = (unsigned short*)(ws + 83886080ull);  // 256 KiB
  unsigned short* ridx = (unsigned short*)(ws + 84148224ull);    // 256 KiB
  int* colCnt = (int*)(ws + 84410368ull);                      // 32 KiB
  int* rcnt = (int*)(ws + 84443136ull);                        // 32 KiB
  int* crowCnt = (int*)(ws + 84475904ull);                     // 32 KiB
  float* rs = (float*)(ws + 84508672ull);                      // 32 KiB
  float* shalf = (float*)(ws + 84541440ull);                   // 32 KiB
  float* sq = (float*)(ws + 84574208ull);                      // 32 KiB
  const size_t WS_NEEDED = 84606976ull;
  if (ws_size < WS_NEEDED) return;

  float* dist = out;  // d_out hosts d^2 until topk_collect finishes

  hipMemsetAsync(rs, 0, N * sizeof(float), stream);
  hipMemsetAsync(crowCnt, 0, N * sizeof(int), stream);
  prep_kernel<<<N, 256, 0, stream>>>(z, zh, zl, sq);
  gemm_dist<<<dim3(64, 64), 256, 0, stream>>>(zh, zl, sq, dist);
  topk_collect<<<N, 256, 0, stream>>>(dist, colIdx, colCnt, rs);
  rlist_kernel<<<N / 256, 256, 0, stream>>>(colIdx, colCnt, rs, ridx, rcnt, shalf);
  crowbuild_kernel<<<N / 256, 256, 0, stream>>>(colIdx, colCnt, crow, crowCnt);
  hipMemsetAsync(out, 0, (size_t)N * N * sizeof(float), stream);
  scatter_kernel<<<N / 4, 256, 0, stream>>>(ridx, rcnt, crow, crowCnt, shalf, out);
}

// Round 9
// 633.631 us; speedup vs baseline: 1.9084x; 1.1047x over previous
//
#include <hip/hip_runtime.h>

// ContextualSimilarity, N=8192 D=512 K=5, MI355X gfx950.  v9 == v8 (re-audited;
// v8 never ran: GPU at capacity 5x).
//
// v6 = 700us (gemm_dist 254us, 822MB HBM: the 256MiB d^2 roundtrip). v8/v9:
//  - d^2 never materialized: GEMM epilogue emits per-(row, 64-col span)
//    top-5 candidates of v = sq[col] - 2*<z_i,z_j> (row-constant sq_i
//    dropped; order-preserving; self still row-min).
//  - TRIANGLE grid: dist symmetric -> 2080 block-pairs (bi<=bj), each
//    off-diag block emits candidates for BOTH orientations via the LDS
//    transpose. GEMM FLOPs halved vs v6.
//  - LDS overlay: epilogue trans buffer aliases the (dead) staging
//    buffers; LDS stays 32.5 KiB.
// candreduce merges 128 spans/row -> kth, colIdx, rs. Sparse epilogue
// (rlist/crowbuild/scatter) unchanged from v6 (passed).
//
// Pipeline: memset(out) -> prep -> gemm_topk -> candreduce -> rlist ->
//           crowbuild -> scatter.   ws ~= 110.7 MiB.

#define N 8192
#define DIM 512
#define KNN 5
#define CROW_CAP 4096

typedef _Float16 half_t;
typedef __attribute__((ext_vector_type(8))) _Float16 f16x8;
typedef __attribute__((ext_vector_type(4))) float f32x4;

#define GLOAD_LDS16(gp, lp) __builtin_amdgcn_global_load_lds( \
    (const __attribute__((address_space(1))) void*)(gp),      \
    (__attribute__((address_space(3))) void*)(lp), 16, 0, 0)

// insertion into sorted-5 (ascending), strict <, with index
#define INS5(val, idx)                                            \
  {                                                               \
    const float v_ = (val);                                       \
    if (v_ < tv[4]) {                                             \
      tv[4] = v_; tix[4] = (idx);                                 \
      if (tv[4] < tv[3]) { float x = tv[3]; tv[3] = tv[4]; tv[4] = x; \
                           int y = tix[3]; tix[3] = tix[4]; tix[4] = y; } \
      if (tv[3] < tv[2]) { float x = tv[2]; tv[2] = tv[3]; tv[3] = x; \
                           int y = tix[2]; tix[2] = tix[3]; tix[3] = y; } \
      if (tv[2] < tv[1]) { float x = tv[1]; tv[1] = tv[2]; tv[2] = x; \
                           int y = tix[1]; tix[1] = tix[2]; tix[2] = y; } \
      if (tv[1] < tv[0]) { float x = tv[0]; tv[0] = tv[1]; tv[1] = x; \
                           int y = tix[0]; tix[0] = tix[1]; tix[1] = y; } \
    }                                                             \
  }

#define CE5(a, b)                                                 \
  {                                                               \
    if (tv[b] < tv[a]) {                                          \
      float x = tv[a]; tv[a] = tv[b]; tv[b] = x;                  \
      int y = tix[a]; tix[a] = tix[b]; tix[b] = y;                \
    }                                                             \
  }

// merge other sorted-5 (ov/oix) into mine (tv/tix), keep 5 smallest sorted.
#define MERGE5()                                                  \
  {                                                               \
    _Pragma("unroll")                                             \
    for (int s_ = 0; s_ < 5; ++s_) {                              \
      if (ov[4 - s_] < tv[s_]) { tv[s_] = ov[4 - s_]; tix[s_] = oix[4 - s_]; } \
    }                                                             \
    CE5(0, 1) CE5(3, 4) CE5(2, 4) CE5(2, 3) CE5(1, 4)             \
    CE5(0, 3) CE5(0, 2) CE5(1, 3) CE5(1, 2)                       \
  }

// ---------------------------------------------------------------- prep
__global__ __launch_bounds__(256) void prep_kernel(
    const float* __restrict__ z, half_t* __restrict__ zh,
    half_t* __restrict__ zl, float* __restrict__ sq) {
  const int row = blockIdx.x;
  const int t = threadIdx.x;
  float s = 0.f;
#pragma unroll
  for (int it = 0; it < DIM / 256; ++it) {
    const int c = t + it * 256;
    const float v = z[(size_t)row * DIM + c];
    s += v * v;
    const half_t h = (half_t)v;
    zh[(size_t)row * DIM + c] = h;
    zl[(size_t)row * DIM + c] = (half_t)(v - (float)h);
  }
  __shared__ float red[256];
  red[t] = s;
  __syncthreads();
  for (int st = 128; st > 0; st >>= 1) {
    if (t < st) red[t] += red[t + st];
    __syncthreads();
  }
  if (t == 0) sq[row] = red[0];
}

// ------------------------------------------- dist GEMM + top-5 candidates
// Triangle grid (bi<=bj), 128x128 tile, 4 waves (2x2), BK=32, fp16-split.
// Off-diag blocks emit candidates for both orientations via LDS transpose.
__global__ __launch_bounds__(256) void gemm_topk(
    const half_t* __restrict__ zh, const half_t* __restrict__ zl,
    const float* __restrict__ sq, float* __restrict__ candV,
    unsigned short* __restrict__ candI) {
  __shared__ __align__(16) unsigned char smem[33280];  // stage(32K) | trans(33.3K) overlay
  half_t* sAh = (half_t*)smem;
  half_t* sAl = (half_t*)(smem + 8192);
  half_t* sBh = (half_t*)(smem + 16384);
  half_t* sBl = (half_t*)(smem + 24576);

  // XCD swizzle (2080 = 8*260, bijective) + triangle decode
  const int id = blockIdx.x;
  int t = (id & 7) * 260 + (id >> 3);
  int bi = 0;
  {
    int rem = t;
    while (rem >= 64 - bi) { rem -= 64 - bi; ++bi; }
    t = rem;
  }
  const int bj = bi + t;

  const int tid = threadIdx.x;
  const int lane = tid & 63, wave = tid >> 6;
  const int wr = wave >> 1, wc = wave & 1;
  const int r0 = tid >> 2, c0 = (tid & 3) * 8;

  f32x4 acc[4][4] = {};

  const size_t a0 = (size_t)(bi * 128 + r0) * DIM + c0;
  const size_t a1 = a0 + (size_t)64 * DIM;
  const size_t b0 = (size_t)(bj * 128 + r0) * DIM + c0;
  const size_t b1 = b0 + (size_t)64 * DIM;
  const int l0 = r0 * 32 + c0, l1 = l0 + 64 * 32;

  for (int k0 = 0; k0 < DIM; k0 += 32) {
    GLOAD_LDS16(zh + a0 + k0, &sAh[l0]);
    GLOAD_LDS16(zh + a1 + k0, &sAh[l1]);
    GLOAD_LDS16(zl + a0 + k0, &sAl[l0]);
    GLOAD_LDS16(zl + a1 + k0, &sAl[l1]);
    GLOAD_LDS16(zh + b0 + k0, &sBh[l0]);
    GLOAD_LDS16(zh + b1 + k0, &sBh[l1]);
    GLOAD_LDS16(zl + b0 + k0, &sBl[l0]);
    GLOAD_LDS16(zl + b1 + k0, &sBl[l1]);
    __syncthreads();
    const int lr = lane & 15, lk = (lane >> 4) * 8;
    f16x8 ah[4], al[4], bh[4], bl[4];
#pragma unroll
    for (int m = 0; m < 4; ++m) {
      const int off = (wr * 64 + m * 16 + lr) * 32 + lk;
      ah[m] = *(const f16x8*)&sAh[off];
      al[m] = *(const f16x8*)&sAl[off];
    }
#pragma unroll
    for (int n = 0; n < 4; ++n) {
      const int off = (wc * 64 + n * 16 + lr) * 32 + lk;
      bh[n] = *(const f16x8*)&sBh[off];
      bl[n] = *(const f16x8*)&sBl[off];
    }
#pragma unroll
    for (int m = 0; m < 4; ++m)
#pragma unroll
      for (int n = 0; n < 4; ++n) {
        acc[m][n] = __builtin_amdgcn_mfma_f32_16x16x32_f16(ah[m], bh[n], acc[m][n], 0, 0, 0);
        acc[m][n] = __builtin_amdgcn_mfma_f32_16x16x32_f16(ah[m], bl[n], acc[m][n], 0, 0, 0);
        acc[m][n] = __builtin_amdgcn_mfma_f32_16x16x32_f16(al[m], bh[n], acc[m][n], 0, 0, 0);
      }
    __syncthreads();
  }
  // stage buffers dead; trans overlays them.
  float* twave = (float*)smem + wave * (32 * 65);  // [32][65] per wave

  // C/D layout: col = lane&15, row = (lane>>4)*4 + reg  [measured m89/m91]
  const int lcol = lane & 15, lr4 = (lane >> 4) * 4;
  const int rowbase = bi * 128 + wr * 64;   // A-rows of this wave's tile
  const int colbase = bj * 128 + wc * 64;   // B-rows (cols) of this wave's tile
  const int rrd = lane >> 1, ch = lane & 1; // read-back assignment

  // ---- orientation 0: rows = A-strip, candidate indices = B-strip ----
  float sqc[4];
#pragma unroll
  for (int n = 0; n < 4; ++n) sqc[n] = sq[colbase + n * 16 + lcol];
#pragma unroll
  for (int h = 0; h < 2; ++h) {
#pragma unroll
    for (int m2 = 0; m2 < 2; ++m2) {
      const int m = 2 * h + m2;
#pragma unroll
      for (int n = 0; n < 4; ++n)
#pragma unroll
        for (int rr = 0; rr < 4; ++rr)
          twave[(m2 * 16 + lr4 + rr) * 65 + n * 16 + lcol] =
              sqc[n] - 2.0f * acc[m][n][rr];
    }
    __syncthreads();
    float tv[5] = {1e30f, 1e30f, 1e30f, 1e30f, 1e30f};
    int tix[5] = {0, 0, 0, 0, 0};
#pragma unroll
    for (int s = 0; s < 32; ++s) {
      const float v = twave[rrd * 65 + ch * 32 + s];
      INS5(v, colbase + ch * 32 + s);
    }
    float ov[5];
    int oix[5];
#pragma unroll
    for (int s = 0; s < 5; ++s) {
      ov[s] = __shfl_xor(tv[s], 1);
      oix[s] = __shfl_xor(tix[s], 1);
    }
    MERGE5();
    if (ch == 0) {
      const int grow = rowbase + h * 32 + rrd;
      const int span = bj * 2 + wc;
      const size_t base = ((size_t)grow * 128 + span) * 5;
#pragma unroll
      for (int s = 0; s < 5; ++s) {
        candV[base + s] = tv[s];
        candI[base + s] = (unsigned short)tix[s];
      }
    }
    __syncthreads();
  }

  // ---- orientation 1 (off-diag): rows = B-strip, indices = A-strip ----
  if (bi != bj) {
    float sqr[16];
#pragma unroll
    for (int m = 0; m < 4; ++m)
#pragma unroll
      for (int rr = 0; rr < 4; ++rr)
        sqr[m * 4 + rr] = sq[rowbase + m * 16 + lr4 + rr];
#pragma unroll
    for (int hc = 0; hc < 2; ++hc) {
#pragma unroll
      for (int n2 = 0; n2 < 2; ++n2) {
        const int n = 2 * hc + n2;
        const int crow = n2 * 16 + lcol;
#pragma unroll
        for (int m = 0; m < 4; ++m)
#pragma unroll
          for (int rr = 0; rr < 4; ++rr)
            twave[crow * 65 + m * 16 + lr4 + rr] =
                sqr[m * 4 + rr] - 2.0f * acc[m][n][rr];
      }
      __syncthreads();
      float tv[5] = {1e30f, 1e30f, 1e30f, 1e30f, 1e30f};
      int tix[5] = {0, 0, 0, 0, 0};
#pragma unroll
      for (int s = 0; s < 32; ++s) {
        const float v = twave[rrd * 65 + ch * 32 + s];
        INS5(v, rowbase + ch * 32 + s);
      }
      float ov[5];
      int oix[5];
#pragma unroll
      for (int s = 0; s < 5; ++s) {
        ov[s] = __shfl_xor(tv[s], 1);
        oix[s] = __shfl_xor(tix[s], 1);
      }
      MERGE5();
      if (ch == 0) {
        const int grow = colbase + hc * 32 + rrd;
        const int span = bi * 2 + wr;
        const size_t base = ((size_t)grow * 128 + span) * 5;
#pragma unroll
        for (int s = 0; s < 5; ++s) {
          candV[base + s] = tv[s];
          candI[base + s] = (unsigned short)tix[s];
        }
      }
      __syncthreads();
    }
  }
}

// --------------------------------- reduce 128 spans/row -> kth + collect
__global__ __launch_bounds__(256) void candreduce_kernel(
    const float* __restrict__ candV, const unsigned short* __restrict__ candI,
    unsigned short* __restrict__ colIdx, int* __restrict__ colCnt,
    float* __restrict__ rs) {
  __shared__ int cnt[4];
  const int tid = threadIdx.x;
  const int wv = tid >> 6, lane = tid & 63;
  const int row = blockIdx.x * 4 + wv;
  if (tid < 4) cnt[tid] = 0;
  __syncthreads();

  const size_t base = (size_t)row * 640 + lane * 10;
  float v[10];
  int ix[10];
#pragma unroll
  for (int q = 0; q < 10; ++q) {
    v[q] = candV[base + q];
    ix[q] = candI[base + q];
  }
  float tv[5] = {1e30f, 1e30f, 1e30f, 1e30f, 1e30f};
  int tix[5] = {0, 0, 0, 0, 0};
#pragma unroll
  for (int q = 0; q < 10; ++q) INS5(v[q], ix[q]);

#pragma unroll
  for (int st = 1; st < 64; st <<= 1) {
    float ov[5];
    int oix[5];
#pragma unroll
    for (int s = 0; s < 5; ++s) {
      ov[s] = __shfl_xor(tv[s], st);
      oix[s] = __shfl_xor(tix[s], st);
    }
    MERGE5();
  }
  const float kth = tv[4];

#pragma unroll
  for (int q = 0; q < 10; ++q) {
    if (v[q] <= kth) {
      const int p = atomicAdd(&cnt[wv], 1);
      if (p < 16) {
        colIdx[row * 16 + p] = (unsigned short)ix[q];
        atomicAdd(&rs[ix[q]], 1.0f);
      }
    }
  }
  __syncthreads();
  if (tid < 4) {
    const int c = cnt[tid];
    colCnt[blockIdx.x * 4 + tid] = (c < 16) ? c : 16;
  }
}

// ------------------------------------------------------- R lists + shalf
__global__ __launch_bounds__(256) void rlist_kernel(
    const unsigned short* __restrict__ colIdx, const int* __restrict__ colCnt,
    const float* __restrict__ rs, unsigned short* __restrict__ ridx,
    int* __restrict__ rcnt, float* __restrict__ shalf) {
  const int j = blockIdx.x * 256 + threadIdx.x;
  if (j >= N) return;
  const int cj = colCnt[j];
  int rc = 0;
  for (int t = 0; t < cj; ++t) {
    const int k = colIdx[j * 16 + t];
    const int ck = colCnt[k];
    bool found = false;
    for (int u = 0; u < ck; ++u) found |= (colIdx[k * 16 + u] == (unsigned short)j);
    if (found) { ridx[j * 16 + rc] = (unsigned short)k; ++rc; }
  }
  rcnt[j] = rc;                                  // rR_j >= 1 (diag of R)
  shalf[j] = 0.5f / (rs[j] * (float)rc);         // 0.5 * s_j
}

// ----------------------------------------------------- sparse C row build
__global__ __launch_bounds__(256) void crowbuild_kernel(
    const unsigned short* __restrict__ colIdx, const int* __restrict__ colCnt,
    unsigned short* __restrict__ crow, int* __restrict__ crowCnt) {
  const int j = blockIdx.x * 256 + threadIdx.x;
  if (j >= N) return;
  const int cj = colCnt[j];
  unsigned short list[16];
  for (int t = 0; t < cj; ++t) list[t] = colIdx[j * 16 + t];
  for (int t = 0; t < cj; ++t) {
    const int k = list[t];
    const int base = atomicAdd(&crowCnt[k], cj);
    for (int u = 0; u < cj; ++u)
      if (base + u < CROW_CAP) crow[(size_t)k * CROW_CAP + base + u] = list[u];
  }
}

// ------------------------------------------------------------- scatter
__global__ __launch_bounds__(256) void scatter_kernel(
    const unsigned short* __restrict__ ridx, const int* __restrict__ rcnt,
    const unsigned short* __restrict__ crow, const int* __restrict__ crowCnt,
    const float* __restrict__ shalf, float* __restrict__ out) {
  const int tid = threadIdx.x;
  const int lane = tid & 63;
  const int j = blockIdx.x * 4 + (tid >> 6);
  const int rc = rcnt[j];
  for (int t = 0; t < rc; ++t) {
    const int k = ridx[j * 16 + t];
    int len = crowCnt[k];
    if (len > CROW_CAP) len = CROW_CAP;
    for (int e = lane; e < len; e += 64) {
      const int a = crow[(size_t)k * CROW_CAP + e];
      const float v = shalf[a];
      atomicAdd(&out[(size_t)a * N + j], v);
      atomicAdd(&out[(size_t)j * N + a], v);
    }
  }
}

// ---------------------------------------------------------------- launch
extern "C" void kernel_launch(void* const* d_in, const int* in_sizes, int n_in,
                              void* d_out, int out_size, void* d_ws,
                              size_t ws_size, hipStream_t stream) {
  const float* z = (const float*)d_in[0];
  float* out = (float*)d_out;
  char* ws = (char*)d_ws;

  // ws layout (~110.7 MiB)
  half_t* zh = (half_t*)ws;                                    // 8 MiB
  half_t* zl = (half_t*)(ws + 8388608ull);                     // 8 MiB
  unsigned short* crow = (unsigned short*)(ws + 16777216ull);  // 64 MiB
  float* candV = (float*)(ws + 83886080ull);                   // 20.97 MB
  unsigned short* candI = (unsigned short*)(ws + 104857600ull);  // 10.49 MB
  unsigned short* colIdx = (unsigned short*)(ws + 115343360ull); // 256 KiB
  unsigned short* ridx = (unsigned short*)(ws + 115605504ull);   // 256 KiB
  int* colCnt = (int*)(ws + 115867648ull);                     // 32 KiB
  int* rcnt = (int*)(ws + 115900416ull);                       // 32 KiB
  int* crowCnt = (int*)(ws + 115933184ull);                    // 32 KiB
  float* rs = (float*)(ws + 115965952ull);                     // 32 KiB
  float* shalf = (float*)(ws + 115998720ull);                  // 32 KiB
  float* sq = (float*)(ws + 116031488ull);                     // 32 KiB
  const size_t WS_NEEDED = 116064256ull;
  if (ws_size < WS_NEEDED) return;

  hipMemsetAsync(out, 0, (size_t)N * N * sizeof(float), stream);
  hipMemsetAsync(rs, 0, N * sizeof(float), stream);
  hipMemsetAsync(crowCnt, 0, N * sizeof(int), stream);
  prep_kernel<<<N, 256, 0, stream>>>(z, zh, zl, sq);
  gemm_topk<<<2080, 256, 0, stream>>>(zh, zl, sq, candV, candI);
  candreduce_kernel<<<N / 4, 256, 0, stream>>>(candV, candI, colIdx, colCnt, rs);
  rlist_kernel<<<N / 256, 256, 0, stream>>>(colIdx, colCnt, rs, ridx, rcnt, shalf);
  crowbuild_kernel<<<N / 256, 256, 0, stream>>>(colIdx, colCnt, crow, crowCnt);
  scatter_kernel<<<N / 4, 256, 0, stream>>>(ridx, rcnt, crow, crowCnt, shalf, out);
}

// Round 11
// 531.298 us; speedup vs baseline: 2.2760x; 1.1926x over previous
//
#include <hip/hip_runtime.h>

// ContextualSimilarity, N=8192 D=512 K=5, MI355X gfx950.  v11 == v10
// (re-audited; v10 never ran: GPU at capacity, 6th timeout).
//
// v9 = 634us: gemm_topk 211us (12.7M LDS bank conflicts, MfmaUtil 21%),
// ~420us unaccounted = scatter (3.8M random HBM atomics) + memset(out).
// v10/v11:
//  - rowout_kernel: out built ROW-LOCALLY in LDS, streamed out coalesced.
//    out[a][j] = 0.5 s_a V[j][a] + 0.5 s_j V[a][j], V[i][j]=sum_{k in ridx[i]}C[k][j];
//    part1: for e in crow[a]: k, for j in ridx[k]: rowbuf[j] += 0.5 s_a
//    part2: for t in ridx[a]: k, for b in crow[k]: rowbuf[b] += 0.5 s_b
//    (uses C=C^T and R=R^T). Deletes scatter + memset(out).
//  - T2 staging swizzle (both-sides-or-neither, rule 21): global source
//    chunk XOR ((r0>>1)&3), LDS dest linear (gload_lds), same XOR on
//    fragment reads. 8-way -> 2-way (free) ds_read_b128.
//
// Pipeline: prep -> gemm_topk -> candreduce -> rlist -> crowbuild -> rowout.

#define N 8192
#define DIM 512
#define KNN 5
#define CROW_CAP 4096

typedef _Float16 half_t;
typedef __attribute__((ext_vector_type(8))) _Float16 f16x8;
typedef __attribute__((ext_vector_type(4))) float f32x4;

#define GLOAD_LDS16(gp, lp) __builtin_amdgcn_global_load_lds( \
    (const __attribute__((address_space(1))) void*)(gp),      \
    (__attribute__((address_space(3))) void*)(lp), 16, 0, 0)

// insertion into sorted-5 (ascending), strict <, with index
#define INS5(val, idx)                                            \
  {                                                               \
    const float v_ = (val);                                       \
    if (v_ < tv[4]) {                                             \
      tv[4] = v_; tix[4] = (idx);                                 \
      if (tv[4] < tv[3]) { float x = tv[3]; tv[3] = tv[4]; tv[4] = x; \
                           int y = tix[3]; tix[3] = tix[4]; tix[4] = y; } \
      if (tv[3] < tv[2]) { float x = tv[2]; tv[2] = tv[3]; tv[3] = x; \
                           int y = tix[2]; tix[2] = tix[3]; tix[3] = y; } \
      if (tv[2] < tv[1]) { float x = tv[1]; tv[1] = tv[2]; tv[2] = x; \
                           int y = tix[1]; tix[1] = tix[2]; tix[2] = y; } \
      if (tv[1] < tv[0]) { float x = tv[0]; tv[0] = tv[1]; tv[1] = x; \
                           int y = tix[0]; tix[0] = tix[1]; tix[1] = y; } \
    }                                                             \
  }

#define CE5(a, b)                                                 \
  {                                                               \
    if (tv[b] < tv[a]) {                                          \
      float x = tv[a]; tv[a] = tv[b]; tv[b] = x;                  \
      int y = tix[a]; tix[a] = tix[b]; tix[b] = y;                \
    }                                                             \
  }

// merge other sorted-5 (ov/oix) into mine (tv/tix), keep 5 smallest sorted.
#define MERGE5()                                                  \
  {                                                               \
    _Pragma("unroll")                                             \
    for (int s_ = 0; s_ < 5; ++s_) {                              \
      if (ov[4 - s_] < tv[s_]) { tv[s_] = ov[4 - s_]; tix[s_] = oix[4 - s_]; } \
    }                                                             \
    CE5(0, 1) CE5(3, 4) CE5(2, 4) CE5(2, 3) CE5(1, 4)             \
    CE5(0, 3) CE5(0, 2) CE5(1, 3) CE5(1, 2)                       \
  }

// ---------------------------------------------------------------- prep
__global__ __launch_bounds__(256) void prep_kernel(
    const float* __restrict__ z, half_t* __restrict__ zh,
    half_t* __restrict__ zl, float* __restrict__ sq) {
  const int row = blockIdx.x;
  const int t = threadIdx.x;
  float s = 0.f;
#pragma unroll
  for (int it = 0; it < DIM / 256; ++it) {
    const int c = t + it * 256;
    const float v = z[(size_t)row * DIM + c];
    s += v * v;
    const half_t h = (half_t)v;
    zh[(size_t)row * DIM + c] = h;
    zl[(size_t)row * DIM + c] = (half_t)(v - (float)h);
  }
  __shared__ float red[256];
  red[t] = s;
  __syncthreads();
  for (int st = 128; st > 0; st >>= 1) {
    if (t < st) red[t] += red[t + st];
    __syncthreads();
  }
  if (t == 0) sq[row] = red[0];
}

// ------------------------------------------- dist GEMM + top-5 candidates
// Triangle grid (bi<=bj), 128x128 tile, 4 waves (2x2), BK=32, fp16-split.
// Staging XOR-swizzle: physical chunk (r, c) holds logical chunk c^((r>>1)&3).
__global__ __launch_bounds__(256) void gemm_topk(
    const half_t* __restrict__ zh, const half_t* __restrict__ zl,
    const float* __restrict__ sq, float* __restrict__ candV,
    unsigned short* __restrict__ candI) {
  __shared__ __align__(16) unsigned char smem[33280];  // stage(32K) | trans(33.3K)
  half_t* sAh = (half_t*)smem;
  half_t* sAl = (half_t*)(smem + 8192);
  half_t* sBh = (half_t*)(smem + 16384);
  half_t* sBl = (half_t*)(smem + 24576);

  // XCD swizzle (2080 = 8*260, bijective) + triangle decode
  const int id = blockIdx.x;
  int t = (id & 7) * 260 + (id >> 3);
  int bi = 0;
  {
    int rem = t;
    while (rem >= 64 - bi) { rem -= 64 - bi; ++bi; }
    t = rem;
  }
  const int bj = bi + t;

  const int tid = threadIdx.x;
  const int lane = tid & 63, wave = tid >> 6;
  const int wr = wave >> 1, wc = wave & 1;
  const int r0 = tid >> 2;
  // source swizzle: load logical chunk ((tid&3) ^ ((r0>>1)&3)); LDS dest linear.
  const int c0 = ((tid & 3) ^ ((r0 >> 1) & 3)) * 8;

  f32x4 acc[4][4] = {};

  const size_t a0 = (size_t)(bi * 128 + r0) * DIM + c0;
  const size_t a1 = a0 + (size_t)64 * DIM;
  const size_t b0 = (size_t)(bj * 128 + r0) * DIM + c0;
  const size_t b1 = b0 + (size_t)64 * DIM;
  const int l0 = (tid >> 2) * 32 + (tid & 3) * 8, l1 = l0 + 64 * 32;

  for (int k0 = 0; k0 < DIM; k0 += 32) {
    GLOAD_LDS16(zh + a0 + k0, &sAh[l0]);
    GLOAD_LDS16(zh + a1 + k0, &sAh[l1]);
    GLOAD_LDS16(zl + a0 + k0, &sAl[l0]);
    GLOAD_LDS16(zl + a1 + k0, &sAl[l1]);
    GLOAD_LDS16(zh + b0 + k0, &sBh[l0]);
    GLOAD_LDS16(zh + b1 + k0, &sBh[l1]);
    GLOAD_LDS16(zl + b0 + k0, &sBl[l0]);
    GLOAD_LDS16(zl + b1 + k0, &sBl[l1]);
    __syncthreads();
    const int lr = lane & 15;
    f16x8 ah[4], al[4], bh[4], bl[4];
#pragma unroll
    for (int m = 0; m < 4; ++m) {
      const int row = wr * 64 + m * 16 + lr;
      const int lks = ((lane >> 4) ^ ((row >> 1) & 3)) * 8;  // read-side XOR
      const int off = row * 32 + lks;
      ah[m] = *(const f16x8*)&sAh[off];
      al[m] = *(const f16x8*)&sAl[off];
    }
#pragma unroll
    for (int n = 0; n < 4; ++n) {
      const int row = wc * 64 + n * 16 + lr;
      const int lks = ((lane >> 4) ^ ((row >> 1) & 3)) * 8;
      const int off = row * 32 + lks;
      bh[n] = *(const f16x8*)&sBh[off];
      bl[n] = *(const f16x8*)&sBl[off];
    }
#pragma unroll
    for (int m = 0; m < 4; ++m)
#pragma unroll
      for (int n = 0; n < 4; ++n) {
        acc[m][n] = __builtin_amdgcn_mfma_f32_16x16x32_f16(ah[m], bh[n], acc[m][n], 0, 0, 0);
        acc[m][n] = __builtin_amdgcn_mfma_f32_16x16x32_f16(ah[m], bl[n], acc[m][n], 0, 0, 0);
        acc[m][n] = __builtin_amdgcn_mfma_f32_16x16x32_f16(al[m], bh[n], acc[m][n], 0, 0, 0);
      }
    __syncthreads();
  }
  // stage buffers dead; trans overlays them.
  float* twave = (float*)smem + wave * (32 * 65);  // [32][65] per wave

  // C/D layout: col = lane&15, row = (lane>>4)*4 + reg  [measured m89/m91]
  const int lcol = lane & 15, lr4 = (lane >> 4) * 4;
  const int rowbase = bi * 128 + wr * 64;   // A-rows of this wave's tile
  const int colbase = bj * 128 + wc * 64;   // B-rows (cols) of this wave's tile
  const int rrd = lane >> 1, ch = lane & 1; // read-back assignment

  // ---- orientation 0: rows = A-strip, candidate indices = B-strip ----
  float sqc[4];
#pragma unroll
  for (int n = 0; n < 4; ++n) sqc[n] = sq[colbase + n * 16 + lcol];
#pragma unroll
  for (int h = 0; h < 2; ++h) {
#pragma unroll
    for (int m2 = 0; m2 < 2; ++m2) {
      const int m = 2 * h + m2;
#pragma unroll
      for (int n = 0; n < 4; ++n)
#pragma unroll
        for (int rr = 0; rr < 4; ++rr)
          twave[(m2 * 16 + lr4 + rr) * 65 + n * 16 + lcol] =
              sqc[n] - 2.0f * acc[m][n][rr];
    }
    __syncthreads();
    float tv[5] = {1e30f, 1e30f, 1e30f, 1e30f, 1e30f};
    int tix[5] = {0, 0, 0, 0, 0};
#pragma unroll
    for (int s = 0; s < 32; ++s) {
      const float v = twave[rrd * 65 + ch * 32 + s];
      INS5(v, colbase + ch * 32 + s);
    }
    float ov[5];
    int oix[5];
#pragma unroll
    for (int s = 0; s < 5; ++s) {
      ov[s] = __shfl_xor(tv[s], 1);
      oix[s] = __shfl_xor(tix[s], 1);
    }
    MERGE5();
    if (ch == 0) {
      const int grow = rowbase + h * 32 + rrd;
      const int span = bj * 2 + wc;
      const size_t base = ((size_t)grow * 128 + span) * 5;
#pragma unroll
      for (int s = 0; s < 5; ++s) {
        candV[base + s] = tv[s];
        candI[base + s] = (unsigned short)tix[s];
      }
    }
    __syncthreads();
  }

  // ---- orientation 1 (off-diag): rows = B-strip, indices = A-strip ----
  if (bi != bj) {
    float sqr[16];
#pragma unroll
    for (int m = 0; m < 4; ++m)
#pragma unroll
      for (int rr = 0; rr < 4; ++rr)
        sqr[m * 4 + rr] = sq[rowbase + m * 16 + lr4 + rr];
#pragma unroll
    for (int hc = 0; hc < 2; ++hc) {
#pragma unroll
      for (int n2 = 0; n2 < 2; ++n2) {
        const int n = 2 * hc + n2;
        const int crow2 = n2 * 16 + lcol;
#pragma unroll
        for (int m = 0; m < 4; ++m)
#pragma unroll
          for (int rr = 0; rr < 4; ++rr)
            twave[crow2 * 65 + m * 16 + lr4 + rr] =
                sqr[m * 4 + rr] - 2.0f * acc[m][n][rr];
      }
      __syncthreads();
      float tv[5] = {1e30f, 1e30f, 1e30f, 1e30f, 1e30f};
      int tix[5] = {0, 0, 0, 0, 0};
#pragma unroll
      for (int s = 0; s < 32; ++s) {
        const float v = twave[rrd * 65 + ch * 32 + s];
        INS5(v, rowbase + ch * 32 + s);
      }
      float ov[5];
      int oix[5];
#pragma unroll
      for (int s = 0; s < 5; ++s) {
        ov[s] = __shfl_xor(tv[s], 1);
        oix[s] = __shfl_xor(tix[s], 1);
      }
      MERGE5();
      if (ch == 0) {
        const int grow = colbase + hc * 32 + rrd;
        const int span = bi * 2 + wr;
        const size_t base = ((size_t)grow * 128 + span) * 5;
#pragma unroll
        for (int s = 0; s < 5; ++s) {
          candV[base + s] = tv[s];
          candI[base + s] = (unsigned short)tix[s];
        }
      }
      __syncthreads();
    }
  }
}

// --------------------------------- reduce 128 spans/row -> kth + collect
__global__ __launch_bounds__(256) void candreduce_kernel(
    const float* __restrict__ candV, const unsigned short* __restrict__ candI,
    unsigned short* __restrict__ colIdx, int* __restrict__ colCnt,
    float* __restrict__ rs) {
  __shared__ int cnt[4];
  const int tid = threadIdx.x;
  const int wv = tid >> 6, lane = tid & 63;
  const int row = blockIdx.x * 4 + wv;
  if (tid < 4) cnt[tid] = 0;
  __syncthreads();

  const size_t base = (size_t)row * 640 + lane * 10;
  float v[10];
  int ix[10];
#pragma unroll
  for (int q = 0; q < 10; ++q) {
    v[q] = candV[base + q];
    ix[q] = candI[base + q];
  }
  float tv[5] = {1e30f, 1e30f, 1e30f, 1e30f, 1e30f};
  int tix[5] = {0, 0, 0, 0, 0};
#pragma unroll
  for (int q = 0; q < 10; ++q) INS5(v[q], ix[q]);

#pragma unroll
  for (int st = 1; st < 64; st <<= 1) {
    float ov[5];
    int oix[5];
#pragma unroll
    for (int s = 0; s < 5; ++s) {
      ov[s] = __shfl_xor(tv[s], st);
      oix[s] = __shfl_xor(tix[s], st);
    }
    MERGE5();
  }
  const float kth = tv[4];

#pragma unroll
  for (int q = 0; q < 10; ++q) {
    if (v[q] <= kth) {
      const int p = atomicAdd(&cnt[wv], 1);
      if (p < 16) {
        colIdx[row * 16 + p] = (unsigned short)ix[q];
        atomicAdd(&rs[ix[q]], 1.0f);
      }
    }
  }
  __syncthreads();
  if (tid < 4) {
    const int c = cnt[tid];
    colCnt[blockIdx.x * 4 + tid] = (c < 16) ? c : 16;
  }
}

// ------------------------------------------------------- R lists + shalf
__global__ __launch_bounds__(256) void rlist_kernel(
    const unsigned short* __restrict__ colIdx, const int* __restrict__ colCnt,
    const float* __restrict__ rs, unsigned short* __restrict__ ridx,
    int* __restrict__ rcnt, float* __restrict__ shalf) {
  const int j = blockIdx.x * 256 + threadIdx.x;
  if (j >= N) return;
  const int cj = colCnt[j];
  int rc = 0;
  for (int t = 0; t < cj; ++t) {
    const int k = colIdx[j * 16 + t];
    const int ck = colCnt[k];
    bool found = false;
    for (int u = 0; u < ck; ++u) found |= (colIdx[k * 16 + u] == (unsigned short)j);
    if (found) { ridx[j * 16 + rc] = (unsigned short)k; ++rc; }
  }
  rcnt[j] = rc;                                  // rR_j >= 1 (diag of R)
  shalf[j] = 0.5f / (rs[j] * (float)rc);         // 0.5 * s_j
}

// ----------------------------------------------------- sparse C row build
__global__ __launch_bounds__(256) void crowbuild_kernel(
    const unsigned short* __restrict__ colIdx, const int* __restrict__ colCnt,
    unsigned short* __restrict__ crow, int* __restrict__ crowCnt) {
  const int j = blockIdx.x * 256 + threadIdx.x;
  if (j >= N) return;
  const int cj = colCnt[j];
  unsigned short list[16];
  for (int t = 0; t < cj; ++t) list[t] = colIdx[j * 16 + t];
  for (int t = 0; t < cj; ++t) {
    const int k = list[t];
    const int base = atomicAdd(&crowCnt[k], cj);
    for (int u = 0; u < cj; ++u)
      if (base + u < CROW_CAP) crow[(size_t)k * CROW_CAP + base + u] = list[u];
  }
}

// ------------------------------------------------- row-local output build
// out[a][j] = 0.5 s_a V[j][a] + 0.5 s_j V[a][j],  V[i][j]=sum_{k in ridx[i]}C[k][j]
// part1 (0.5 s_a V[j][a]): for e in crow[a]: k, for j in ridx[k]: += 0.5 s_a
// part2 (0.5 s_b V[a][b]): for t in ridx[a]: k, for b in crow[k]: += 0.5 s_b
// 4 rows/block, 8 waves (2 per row: part1 | part2), LDS atomics, dense write.
__global__ __launch_bounds__(512) void rowout_kernel(
    const unsigned short* __restrict__ ridx, const int* __restrict__ rcnt,
    const unsigned short* __restrict__ crow, const int* __restrict__ crowCnt,
    const float* __restrict__ shalf, float* __restrict__ out) {
  __shared__ float rowbuf[4][N];  // 128 KiB
  const int tid = threadIdx.x;
  const int wave = tid >> 6, lane = tid & 63;
  const int r = wave >> 1, half = wave & 1;
  const int a = blockIdx.x * 4 + r;

  // zero my half-row (4096 floats = 16 float4 per lane)
  float4* zp = (float4*)&rowbuf[r][half * (N / 2)];
#pragma unroll
  for (int u = 0; u < 16; ++u) zp[lane + u * 64] = make_float4(0.f, 0.f, 0.f, 0.f);
  __syncthreads();

  if (half == 0) {
    const float va = shalf[a];
    int len = crowCnt[a];
    if (len > CROW_CAP) len = CROW_CAP;
    for (int e = lane; e < len; e += 64) {
      const int k = crow[(size_t)a * CROW_CAP + e];
      const int rc = rcnt[k];
      for (int u = 0; u < rc; ++u)
        atomicAdd(&rowbuf[r][ridx[k * 16 + u]], va);
    }
  } else {
    const int rc = rcnt[a];
    for (int t = 0; t < rc; ++t) {
      const int k = ridx[a * 16 + t];
      int len = crowCnt[k];
      if (len > CROW_CAP) len = CROW_CAP;
      for (int e = lane; e < len; e += 64) {
        const int b = crow[(size_t)k * CROW_CAP + e];
        atomicAdd(&rowbuf[r][b], shalf[b]);
      }
    }
  }
  __syncthreads();

  // stream the dense row out (coalesced)
  const float4* src = (const float4*)&rowbuf[r][half * (N / 2)];
  float4* dst = (float4*)(out + (size_t)a * N + half * (N / 2));
#pragma unroll
  for (int u = 0; u < 16; ++u) dst[lane + u * 64] = src[lane + u * 64];
}

// ---------------------------------------------------------------- launch
extern "C" void kernel_launch(void* const* d_in, const int* in_sizes, int n_in,
                              void* d_out, int out_size, void* d_ws,
                              size_t ws_size, hipStream_t stream) {
  const float* z = (const float*)d_in[0];
  float* out = (float*)d_out;
  char* ws = (char*)d_ws;

  // ws layout (~110.7 MiB)
  half_t* zh = (half_t*)ws;                                    // 8 MiB
  half_t* zl = (half_t*)(ws + 8388608ull);                     // 8 MiB
  unsigned short* crow = (unsigned short*)(ws + 16777216ull);  // 64 MiB
  float* candV = (float*)(ws + 83886080ull);                   // 20.97 MB
  unsigned short* candI = (unsigned short*)(ws + 104857600ull);  // 10.49 MB
  unsigned short* colIdx = (unsigned short*)(ws + 115343360ull); // 256 KiB
  unsigned short* ridx = (unsigned short*)(ws + 115605504ull);   // 256 KiB
  int* colCnt = (int*)(ws + 115867648ull);                     // 32 KiB
  int* rcnt = (int*)(ws + 115900416ull);                       // 32 KiB
  int* crowCnt = (int*)(ws + 115933184ull);                    // 32 KiB
  float* rs = (float*)(ws + 115965952ull);                     // 32 KiB
  float* shalf = (float*)(ws + 115998720ull);                  // 32 KiB
  float* sq = (float*)(ws + 116031488ull);                     // 32 KiB
  const size_t WS_NEEDED = 116064256ull;
  if (ws_size < WS_NEEDED) return;

  hipMemsetAsync(rs, 0, N * sizeof(float), stream);
  hipMemsetAsync(crowCnt, 0, N * sizeof(int), stream);
  prep_kernel<<<N, 256, 0, stream>>>(z, zh, zl, sq);
  gemm_topk<<<2080, 256, 0, stream>>>(zh, zl, sq, candV, candI);
  candreduce_kernel<<<N / 4, 256, 0, stream>>>(candV, candI, colIdx, colCnt, rs);
  rlist_kernel<<<N / 256, 256, 0, stream>>>(colIdx, colCnt, rs, ridx, rcnt, shalf);
  crowbuild_kernel<<<N / 256, 256, 0, stream>>>(colIdx, colCnt, crow, crowCnt);
  rowout_kernel<<<N / 4, 512, 0, stream>>>(ridx, rcnt, crow, crowCnt, shalf, out);
}

// Round 12
// 526.334 us; speedup vs baseline: 2.2974x; 1.0094x over previous
//
#include <hip/hip_runtime.h>

// ContextualSimilarity, N=8192 D=512 K=5, MI355X gfx950.  v12: dispatch fusion.
//
// v11 = 531us. gemm_topk 204us; modeled tail ~120us; ~200us unaccounted ->
// suspected per-dispatch overhead (10 dispatches). v12 reduces to 5 dispatches
// with byte-identical math:
//  - prep zeroes rs/crowCnt (absorbs 2 memsets)
//  - rlist+crowbuild merged (independent, same inputs)
// Pipeline: prep -> gemm_topk -> candreduce -> rlist_crow -> rowout.

#define N 8192
#define DIM 512
#define KNN 5
#define CROW_CAP 4096

typedef _Float16 half_t;
typedef __attribute__((ext_vector_type(8))) _Float16 f16x8;
typedef __attribute__((ext_vector_type(4))) float f32x4;

#define GLOAD_LDS16(gp, lp) __builtin_amdgcn_global_load_lds( \
    (const __attribute__((address_space(1))) void*)(gp),      \
    (__attribute__((address_space(3))) void*)(lp), 16, 0, 0)

// insertion into sorted-5 (ascending), strict <, with index
#define INS5(val, idx)                                            \
  {                                                               \
    const float v_ = (val);                                       \
    if (v_ < tv[4]) {                                             \
      tv[4] = v_; tix[4] = (idx);                                 \
      if (tv[4] < tv[3]) { float x = tv[3]; tv[3] = tv[4]; tv[4] = x; \
                           int y = tix[3]; tix[3] = tix[4]; tix[4] = y; } \
      if (tv[3] < tv[2]) { float x = tv[2]; tv[2] = tv[3]; tv[3] = x; \
                           int y = tix[2]; tix[2] = tix[3]; tix[3] = y; } \
      if (tv[2] < tv[1]) { float x = tv[1]; tv[1] = tv[2]; tv[2] = x; \
                           int y = tix[1]; tix[1] = tix[2]; tix[2] = y; } \
      if (tv[1] < tv[0]) { float x = tv[0]; tv[0] = tv[1]; tv[1] = x; \
                           int y = tix[0]; tix[0] = tix[1]; tix[1] = y; } \
    }                                                             \
  }

#define CE5(a, b)                                                 \
  {                                                               \
    if (tv[b] < tv[a]) {                                          \
      float x = tv[a]; tv[a] = tv[b]; tv[b] = x;                  \
      int y = tix[a]; tix[a] = tix[b]; tix[b] = y;                \
    }                                                             \
  }

// merge other sorted-5 (ov/oix) into mine (tv/tix), keep 5 smallest sorted.
#define MERGE5()                                                  \
  {                                                               \
    _Pragma("unroll")                                             \
    for (int s_ = 0; s_ < 5; ++s_) {                              \
      if (ov[4 - s_] < tv[s_]) { tv[s_] = ov[4 - s_]; tix[s_] = oix[4 - s_]; } \
    }                                                             \
    CE5(0, 1) CE5(3, 4) CE5(2, 4) CE5(2, 3) CE5(1, 4)             \
    CE5(0, 3) CE5(0, 2) CE5(1, 3) CE5(1, 2)                       \
  }

// ------------------------------------------- prep (+ rs/crowCnt zeroing)
__global__ __launch_bounds__(256) void prep_kernel(
    const float* __restrict__ z, half_t* __restrict__ zh,
    half_t* __restrict__ zl, float* __restrict__ sq,
    float* __restrict__ rs, int* __restrict__ crowCnt) {
  const int row = blockIdx.x;
  const int t = threadIdx.x;
  float s = 0.f;
#pragma unroll
  for (int it = 0; it < DIM / 256; ++it) {
    const int c = t + it * 256;
    const float v = z[(size_t)row * DIM + c];
    s += v * v;
    const half_t h = (half_t)v;
    zh[(size_t)row * DIM + c] = h;
    zl[(size_t)row * DIM + c] = (half_t)(v - (float)h);
  }
  __shared__ float red[256];
  red[t] = s;
  __syncthreads();
  for (int st = 128; st > 0; st >>= 1) {
    if (t < st) red[t] += red[t + st];
    __syncthreads();
  }
  if (t == 0) {
    sq[row] = red[0];
    rs[row] = 0.f;      // zero atomic accumulators (replaces memsets)
    crowCnt[row] = 0;
  }
}

// ------------------------------------------- dist GEMM + top-5 candidates
// Triangle grid (bi<=bj), 128x128 tile, 4 waves (2x2), BK=32, fp16-split.
// Staging XOR-swizzle: physical chunk (r, c) holds logical chunk c^((r>>1)&3).
__global__ __launch_bounds__(256) void gemm_topk(
    const half_t* __restrict__ zh, const half_t* __restrict__ zl,
    const float* __restrict__ sq, float* __restrict__ candV,
    unsigned short* __restrict__ candI) {
  __shared__ __align__(16) unsigned char smem[33280];  // stage(32K) | trans(33.3K)
  half_t* sAh = (half_t*)smem;
  half_t* sAl = (half_t*)(smem + 8192);
  half_t* sBh = (half_t*)(smem + 16384);
  half_t* sBl = (half_t*)(smem + 24576);

  // XCD swizzle (2080 = 8*260, bijective) + triangle decode
  const int id = blockIdx.x;
  int t = (id & 7) * 260 + (id >> 3);
  int bi = 0;
  {
    int rem = t;
    while (rem >= 64 - bi) { rem -= 64 - bi; ++bi; }
    t = rem;
  }
  const int bj = bi + t;

  const int tid = threadIdx.x;
  const int lane = tid & 63, wave = tid >> 6;
  const int wr = wave >> 1, wc = wave & 1;
  const int r0 = tid >> 2;
  // source swizzle: load logical chunk ((tid&3) ^ ((r0>>1)&3)); LDS dest linear.
  const int c0 = ((tid & 3) ^ ((r0 >> 1) & 3)) * 8;

  f32x4 acc[4][4] = {};

  const size_t a0 = (size_t)(bi * 128 + r0) * DIM + c0;
  const size_t a1 = a0 + (size_t)64 * DIM;
  const size_t b0 = (size_t)(bj * 128 + r0) * DIM + c0;
  const size_t b1 = b0 + (size_t)64 * DIM;
  const int l0 = (tid >> 2) * 32 + (tid & 3) * 8, l1 = l0 + 64 * 32;

  for (int k0 = 0; k0 < DIM; k0 += 32) {
    GLOAD_LDS16(zh + a0 + k0, &sAh[l0]);
    GLOAD_LDS16(zh + a1 + k0, &sAh[l1]);
    GLOAD_LDS16(zl + a0 + k0, &sAl[l0]);
    GLOAD_LDS16(zl + a1 + k0, &sAl[l1]);
    GLOAD_LDS16(zh + b0 + k0, &sBh[l0]);
    GLOAD_LDS16(zh + b1 + k0, &sBh[l1]);
    GLOAD_LDS16(zl + b0 + k0, &sBl[l0]);
    GLOAD_LDS16(zl + b1 + k0, &sBl[l1]);
    __syncthreads();
    const int lr = lane & 15;
    f16x8 ah[4], al[4], bh[4], bl[4];
#pragma unroll
    for (int m = 0; m < 4; ++m) {
      const int row = wr * 64 + m * 16 + lr;
      const int lks = ((lane >> 4) ^ ((row >> 1) & 3)) * 8;  // read-side XOR
      const int off = row * 32 + lks;
      ah[m] = *(const f16x8*)&sAh[off];
      al[m] = *(const f16x8*)&sAl[off];
    }
#pragma unroll
    for (int n = 0; n < 4; ++n) {
      const int row = wc * 64 + n * 16 + lr;
      const int lks = ((lane >> 4) ^ ((row >> 1) & 3)) * 8;
      const int off = row * 32 + lks;
      bh[n] = *(const f16x8*)&sBh[off];
      bl[n] = *(const f16x8*)&sBl[off];
    }
#pragma unroll
    for (int m = 0; m < 4; ++m)
#pragma unroll
      for (int n = 0; n < 4; ++n) {
        acc[m][n] = __builtin_amdgcn_mfma_f32_16x16x32_f16(ah[m], bh[n], acc[m][n], 0, 0, 0);
        acc[m][n] = __builtin_amdgcn_mfma_f32_16x16x32_f16(ah[m], bl[n], acc[m][n], 0, 0, 0);
        acc[m][n] = __builtin_amdgcn_mfma_f32_16x16x32_f16(al[m], bh[n], acc[m][n], 0, 0, 0);
      }
    __syncthreads();
  }
  // stage buffers dead; trans overlays them.
  float* twave = (float*)smem + wave * (32 * 65);  // [32][65] per wave

  // C/D layout: col = lane&15, row = (lane>>4)*4 + reg  [measured m89/m91]
  const int lcol = lane & 15, lr4 = (lane >> 4) * 4;
  const int rowbase = bi * 128 + wr * 64;   // A-rows of this wave's tile
  const int colbase = bj * 128 + wc * 64;   // B-rows (cols) of this wave's tile
  const int rrd = lane >> 1, ch = lane & 1; // read-back assignment

  // ---- orientation 0: rows = A-strip, candidate indices = B-strip ----
  float sqc[4];
#pragma unroll
  for (int n = 0; n < 4; ++n) sqc[n] = sq[colbase + n * 16 + lcol];
#pragma unroll
  for (int h = 0; h < 2; ++h) {
#pragma unroll
    for (int m2 = 0; m2 < 2; ++m2) {
      const int m = 2 * h + m2;
#pragma unroll
      for (int n = 0; n < 4; ++n)
#pragma unroll
        for (int rr = 0; rr < 4; ++rr)
          twave[(m2 * 16 + lr4 + rr) * 65 + n * 16 + lcol] =
              sqc[n] - 2.0f * acc[m][n][rr];
    }
    __syncthreads();
    float tv[5] = {1e30f, 1e30f, 1e30f, 1e30f, 1e30f};
    int tix[5] = {0, 0, 0, 0, 0};
#pragma unroll
    for (int s = 0; s < 32; ++s) {
      const float v = twave[rrd * 65 + ch * 32 + s];
      INS5(v, colbase + ch * 32 + s);
    }
    float ov[5];
    int oix[5];
#pragma unroll
    for (int s = 0; s < 5; ++s) {
      ov[s] = __shfl_xor(tv[s], 1);
      oix[s] = __shfl_xor(tix[s], 1);
    }
    MERGE5();
    if (ch == 0) {
      const int grow = rowbase + h * 32 + rrd;
      const int span = bj * 2 + wc;
      const size_t base = ((size_t)grow * 128 + span) * 5;
#pragma unroll
      for (int s = 0; s < 5; ++s) {
        candV[base + s] = tv[s];
        candI[base + s] = (unsigned short)tix[s];
      }
    }
    __syncthreads();
  }

  // ---- orientation 1 (off-diag): rows = B-strip, indices = A-strip ----
  if (bi != bj) {
    float sqr[16];
#pragma unroll
    for (int m = 0; m < 4; ++m)
#pragma unroll
      for (int rr = 0; rr < 4; ++rr)
        sqr[m * 4 + rr] = sq[rowbase + m * 16 + lr4 + rr];
#pragma unroll
    for (int hc = 0; hc < 2; ++hc) {
#pragma unroll
      for (int n2 = 0; n2 < 2; ++n2) {
        const int n = 2 * hc + n2;
        const int crow2 = n2 * 16 + lcol;
#pragma unroll
        for (int m = 0; m < 4; ++m)
#pragma unroll
          for (int rr = 0; rr < 4; ++rr)
            twave[crow2 * 65 + m * 16 + lr4 + rr] =
                sqr[m * 4 + rr] - 2.0f * acc[m][n][rr];
      }
      __syncthreads();
      float tv[5] = {1e30f, 1e30f, 1e30f, 1e30f, 1e30f};
      int tix[5] = {0, 0, 0, 0, 0};
#pragma unroll
      for (int s = 0; s < 32; ++s) {
        const float v = twave[rrd * 65 + ch * 32 + s];
        INS5(v, rowbase + ch * 32 + s);
      }
      float ov[5];
      int oix[5];
#pragma unroll
      for (int s = 0; s < 5; ++s) {
        ov[s] = __shfl_xor(tv[s], 1);
        oix[s] = __shfl_xor(tix[s], 1);
      }
      MERGE5();
      if (ch == 0) {
        const int grow = colbase + hc * 32 + rrd;
        const int span = bi * 2 + wr;
        const size_t base = ((size_t)grow * 128 + span) * 5;
#pragma unroll
        for (int s = 0; s < 5; ++s) {
          candV[base + s] = tv[s];
          candI[base + s] = (unsigned short)tix[s];
        }
      }
      __syncthreads();
    }
  }
}

// --------------------------------- reduce 128 spans/row -> kth + collect
__global__ __launch_bounds__(256) void candreduce_kernel(
    const float* __restrict__ candV, const unsigned short* __restrict__ candI,
    unsigned short* __restrict__ colIdx, int* __restrict__ colCnt,
    float* __restrict__ rs) {
  __shared__ int cnt[4];
  const int tid = threadIdx.x;
  const int wv = tid >> 6, lane = tid & 63;
  const int row = blockIdx.x * 4 + wv;
  if (tid < 4) cnt[tid] = 0;
  __syncthreads();

  const size_t base = (size_t)row * 640 + lane * 10;
  float v[10];
  int ix[10];
#pragma unroll
  for (int q = 0; q < 10; ++q) {
    v[q] = candV[base + q];
    ix[q] = candI[base + q];
  }
  float tv[5] = {1e30f, 1e30f, 1e30f, 1e30f, 1e30f};
  int tix[5] = {0, 0, 0, 0, 0};
#pragma unroll
  for (int q = 0; q < 10; ++q) INS5(v[q], ix[q]);

#pragma unroll
  for (int st = 1; st < 64; st <<= 1) {
    float ov[5];
    int oix[5];
#pragma unroll
    for (int s = 0; s < 5; ++s) {
      ov[s] = __shfl_xor(tv[s], st);
      oix[s] = __shfl_xor(tix[s], st);
    }
    MERGE5();
  }
  const float kth = tv[4];

#pragma unroll
  for (int q = 0; q < 10; ++q) {
    if (v[q] <= kth) {
      const int p = atomicAdd(&cnt[wv], 1);
      if (p < 16) {
        colIdx[row * 16 + p] = (unsigned short)ix[q];
        atomicAdd(&rs[ix[q]], 1.0f);
      }
    }
  }
  __syncthreads();
  if (tid < 4) {
    const int c = cnt[tid];
    colCnt[blockIdx.x * 4 + tid] = (c < 16) ? c : 16;
  }
}

// ----------------------------- R lists + shalf + sparse C rows (fused)
// rlist part and crowbuild part both depend only on colIdx/colCnt.
__global__ __launch_bounds__(256) void rlist_crow_kernel(
    const unsigned short* __restrict__ colIdx, const int* __restrict__ colCnt,
    const float* __restrict__ rs, unsigned short* __restrict__ ridx,
    int* __restrict__ rcnt, float* __restrict__ shalf,
    unsigned short* __restrict__ crow, int* __restrict__ crowCnt) {
  const int j = blockIdx.x * 256 + threadIdx.x;
  if (j >= N) return;
  const int cj = colCnt[j];
  unsigned short list[16];
  for (int t = 0; t < cj; ++t) list[t] = colIdx[j * 16 + t];

  // R row list: k in colIdx[j] with j in colIdx[k]
  int rc = 0;
  for (int t = 0; t < cj; ++t) {
    const int k = list[t];
    const int ck = colCnt[k];
    bool found = false;
    for (int u = 0; u < ck; ++u) found |= (colIdx[k * 16 + u] == (unsigned short)j);
    if (found) { ridx[j * 16 + rc] = (unsigned short)k; ++rc; }
  }
  rcnt[j] = rc;                                  // rR_j >= 1 (diag of R)
  shalf[j] = 0.5f / (rs[j] * (float)rc);         // 0.5 * s_j

  // sparse C rows: crow[k] += list (multiplicity = C[k][a])
  for (int t = 0; t < cj; ++t) {
    const int k = list[t];
    const int base = atomicAdd(&crowCnt[k], cj);
    for (int u = 0; u < cj; ++u)
      if (base + u < CROW_CAP) crow[(size_t)k * CROW_CAP + base + u] = list[u];
  }
}

// ------------------------------------------------- row-local output build
// out[a][j] = 0.5 s_a V[j][a] + 0.5 s_j V[a][j],  V[i][j]=sum_{k in ridx[i]}C[k][j]
// part1 (0.5 s_a V[j][a]): for e in crow[a]: k, for j in ridx[k]: += 0.5 s_a
// part2 (0.5 s_b V[a][b]): for t in ridx[a]: k, for b in crow[k]: += 0.5 s_b
// 4 rows/block, 8 waves (2 per row: part1 | part2), LDS atomics, dense write.
__global__ __launch_bounds__(512) void rowout_kernel(
    const unsigned short* __restrict__ ridx, const int* __restrict__ rcnt,
    const unsigned short* __restrict__ crow, const int* __restrict__ crowCnt,
    const float* __restrict__ shalf, float* __restrict__ out) {
  __shared__ float rowbuf[4][N];  // 128 KiB
  const int tid = threadIdx.x;
  const int wave = tid >> 6, lane = tid & 63;
  const int r = wave >> 1, half = wave & 1;
  const int a = blockIdx.x * 4 + r;

  // zero my half-row (4096 floats = 16 float4 per lane)
  float4* zp = (float4*)&rowbuf[r][half * (N / 2)];
#pragma unroll
  for (int u = 0; u < 16; ++u) zp[lane + u * 64] = make_float4(0.f, 0.f, 0.f, 0.f);
  __syncthreads();

  if (half == 0) {
    const float va = shalf[a];
    int len = crowCnt[a];
    if (len > CROW_CAP) len = CROW_CAP;
    for (int e = lane; e < len; e += 64) {
      const int k = crow[(size_t)a * CROW_CAP + e];
      const int rc = rcnt[k];
      for (int u = 0; u < rc; ++u)
        atomicAdd(&rowbuf[r][ridx[k * 16 + u]], va);
    }
  } else {
    const int rc = rcnt[a];
    for (int t = 0; t < rc; ++t) {
      const int k = ridx[a * 16 + t];
      int len = crowCnt[k];
      if (len > CROW_CAP) len = CROW_CAP;
      for (int e = lane; e < len; e += 64) {
        const int b = crow[(size_t)k * CROW_CAP + e];
        atomicAdd(&rowbuf[r][b], shalf[b]);
      }
    }
  }
  __syncthreads();

  // stream the dense row out (coalesced)
  const float4* src = (const float4*)&rowbuf[r][half * (N / 2)];
  float4* dst = (float4*)(out + (size_t)a * N + half * (N / 2));
#pragma unroll
  for (int u = 0; u < 16; ++u) dst[lane + u * 64] = src[lane + u * 64];
}

// ---------------------------------------------------------------- launch
extern "C" void kernel_launch(void* const* d_in, const int* in_sizes, int n_in,
                              void* d_out, int out_size, void* d_ws,
                              size_t ws_size, hipStream_t stream) {
  const float* z = (const float*)d_in[0];
  float* out = (float*)d_out;
  char* ws = (char*)d_ws;

  // ws layout (~110.7 MiB)
  half_t* zh = (half_t*)ws;                                    // 8 MiB
  half_t* zl = (half_t*)(ws + 8388608ull);                     // 8 MiB
  unsigned short* crow = (unsigned short*)(ws + 16777216ull);  // 64 MiB
  float* candV = (float*)(ws + 83886080ull);                   // 20.97 MB
  unsigned short* candI = (unsigned short*)(ws + 104857600ull);  // 10.49 MB
  unsigned short* colIdx = (unsigned short*)(ws + 115343360ull); // 256 KiB
  unsigned short* ridx = (unsigned short*)(ws + 115605504ull);   // 256 KiB
  int* colCnt = (int*)(ws + 115867648ull);                     // 32 KiB
  int* rcnt = (int*)(ws + 115900416ull);                       // 32 KiB
  int* crowCnt = (int*)(ws + 115933184ull);                    // 32 KiB
  float* rs = (float*)(ws + 115965952ull);                     // 32 KiB
  float* shalf = (float*)(ws + 115998720ull);                  // 32 KiB
  float* sq = (float*)(ws + 116031488ull);                     // 32 KiB
  const size_t WS_NEEDED = 116064256ull;
  if (ws_size < WS_NEEDED) return;

  prep_kernel<<<N, 256, 0, stream>>>(z, zh, zl, sq, rs, crowCnt);
  gemm_topk<<<2080, 256, 0, stream>>>(zh, zl, sq, candV, candI);
  candreduce_kernel<<<N / 4, 256, 0, stream>>>(candV, candI, colIdx, colCnt, rs);
  rlist_crow_kernel<<<N / 256, 256, 0, stream>>>(colIdx, colCnt, rs, ridx, rcnt,
                                                 shalf, crow, crowCnt);
  rowout_kernel<<<N / 4, 512, 0, stream>>>(ridx, rcnt, crow, crowCnt, shalf, out);
}